// Round 8
// baseline (169.230 us; speedup 1.0000x reference)
//
#include <hip/hip_runtime.h>
#include <hip/hip_bf16.h>

#define BB 4
#define CC 256
#define CI 128
#define NN 4096

typedef _Float16 f16;
typedef __attribute__((ext_vector_type(8))) _Float16 f16x8;
typedef __attribute__((ext_vector_type(4))) float f32x4;

#define MFMA(a,b,c) __builtin_amdgcn_mfma_f32_16x16x32_f16(a,b,c,0,0,0)
#define LDS3(p) ((__attribute__((address_space(3))) void*)(p))
#define GL1(p)  ((const __attribute__((address_space(1))) void*)(p))

// DPP 16-lane butterfly reduce (1-cy VALU ops, no LDS pipe)
#define DPP_MAX(x, ctrl) { int _s=__float_as_int(x); \
    float _y=__int_as_float(__builtin_amdgcn_update_dpp(_s,_s,ctrl,0xF,0xF,false)); \
    x = fmaxf(x,_y); }
#define DPP_ADD(x, ctrl) { int _s=__float_as_int(x); \
    float _y=__int_as_float(__builtin_amdgcn_update_dpp(_s,_s,ctrl,0xF,0xF,false)); \
    x = x+_y; }
__device__ __forceinline__ float rowmax16(float x){
    DPP_MAX(x,0xB1) DPP_MAX(x,0x4E) DPP_MAX(x,0x141) DPP_MAX(x,0x140) return x;
}
__device__ __forceinline__ float rowsum16(float x){
    DPP_ADD(x,0xB1) DPP_ADD(x,0x4E) DPP_ADD(x,0x141) DPP_ADD(x,0x140) return x;
}

// ---------------- K01: transpose+cast x -> xt, plus weight cast (fused k0) ----------------
__global__ __launch_bounds__(256) void k01_xpose(const float* x, f16* xt,
                                                 const float* tw, const float* pw,
                                                 const float* gw, const float* Ww, f16* wdst){
    int nt = blockIdx.x, ct = blockIdx.y, b = blockIdx.z;
    __shared__ float tile[64][65];
    int t = threadIdx.x;
    const float* src = x + ((size_t)(b*CC + ct*64))*NN + nt*64;
    #pragma unroll
    for (int k=0;k<16;k++){ int idx=t+k*256; int cl=idx>>6, nl=idx&63;
        tile[cl][nl]=src[(size_t)cl*NN + nl]; }
    __syncthreads();
    f16* dst = xt + ((size_t)(b*NN + nt*64))*CC + ct*64;
    #pragma unroll
    for (int k=0;k<16;k++){ int idx=t+k*256; int nl=idx>>6, cl=idx&63;
        dst[(size_t)nl*CC + cl] = (f16)tile[cl][nl]; }
    // fused weight cast: 1024 blocks x 128 elements = 131072
    if (t < 128){
        int blkId = blockIdx.x + 64*(blockIdx.y + 4*blockIdx.z);
        int i = blkId*128 + t;
        int j = i & 32767; int sel = i >> 15;
        const float* s = (sel==0)? tw : (sel==1)? pw : (sel==2)? gw : Ww;
        wdst[i] = (f16)s[j];
    }
}

// ---------------- K2: merged theta/phi/g projections, 512 blocks ----------------
__global__ __launch_bounds__(256) void k2_all(const f16* xt, const f16* thw, const f16* phw,
                                              const f16* gwh, const float* thb, const float* phb,
                                              const float* gb, f16* th, f16* ph, f16* gt2){
    int b = blockIdx.y; int xx = blockIdx.x;
    int wv = threadIdx.x>>6, lane = threadIdx.x&63, q=lane>>4, cc=lane&15;
    if (xx < 64){
        // theta (xx<32) or phi (xx>=32), 128 rows per block
        int mat = xx>>5; int ntile = xx&31;
        int n0 = ntile*128 + wv*32;
        f16x8 aq[2][8];
        #pragma unroll
        for (int ns=0;ns<2;ns++){
            const f16* ap = xt + ((size_t)(b*NN + n0 + ns*16 + cc))*CC + q*8;
            #pragma unroll
            for (int kk=0;kk<8;kk++) aq[ns][kk] = *(const f16x8*)(ap + kk*32);
        }
        const f16* w   = mat? phw : thw;
        const float* bias = mat? phb : thb;
        f16* o = mat? ph : th;
        #pragma unroll 1
        for (int os=0;os<8;os++){
            f32x4 acc0={0,0,0,0}, acc1={0,0,0,0};
            const f16* wp = w + ((size_t)(os*16 + cc))*CC + q*8;
            #pragma unroll
            for (int kk=0;kk<8;kk++){
                f16x8 bf = *(const f16x8*)(wp + kk*32);
                acc0 = MFMA(aq[0][kk], bf, acc0);
                acc1 = MFMA(aq[1][kk], bf, acc1);
            }
            float bv = bias[os*16+cc];
            #pragma unroll
            for (int r=0;r<4;r++){
                o[((size_t)(b*NN + n0      + 4*q + r))*CI + os*16 + cc] = (f16)(acc0[r] + bv);
                o[((size_t)(b*NN + n0 + 16 + 4*q + r))*CI + os*16 + cc] = (f16)(acc1[r] + bv);
            }
        }
    } else {
        // g projection, TILED output gt2[b][mt][o][64]
        int mt = xx - 64;
        f16x8 ag[2][8];
        #pragma unroll
        for (int os=0;os<2;os++){
            const f16* ap = gwh + ((size_t)(wv*32 + os*16 + cc))*CC + q*8;
            #pragma unroll
            for (int kk=0;kk<8;kk++) ag[os][kk] = *(const f16x8*)(ap + kk*32);
        }
        f32x4 acc[2][4];
        #pragma unroll
        for (int os=0;os<2;os++){
            #pragma unroll
            for (int ms=0;ms<4;ms++) acc[os][ms]=(f32x4){0,0,0,0};
        }
        #pragma unroll 1
        for (int kk=0;kk<8;kk++){
            #pragma unroll
            for (int ms=0;ms<4;ms++){
                f16x8 bf = *(const f16x8*)(xt + ((size_t)(b*NN + mt*64 + ms*16 + cc))*CC + kk*32 + q*8);
                acc[0][ms]=MFMA(ag[0][kk],bf,acc[0][ms]);
                acc[1][ms]=MFMA(ag[1][kk],bf,acc[1][ms]);
            }
        }
        #pragma unroll
        for (int os=0;os<2;os++){
            #pragma unroll
            for (int r=0;r<4;r++){
                int orow = wv*32 + os*16 + 4*q + r;
                float bv = gb[orow];
                #pragma unroll
                for (int ms=0;ms<4;ms++)
                    gt2[((size_t)(b*64 + mt))*8192 + orow*64 + ms*16 + cc] = (f16)(acc[os][ms][r] + bv);
            }
        }
    }
}

// ---------------- K3: flash attention, KVBLK=32, 40KB LDS, 3 blocks/CU ----------------
__global__ __launch_bounds__(256, 3) void k3_attn(const f16* th, const f16* ph, const f16* gt2,
                                                  f16* ypart, float* ml){
    int qt = blockIdx.x;           // 32 q-tiles of 128 rows
    int sp = blockIdx.y;           // 4 key splits of 1024 keys
    int b  = blockIdx.z;           // 4 batches
    int wv=threadIdx.x>>6, lane=threadIdx.x&63, q=lane>>4, cc=lane&15;
    int qrow0 = qt*128 + wv*32;
    int kv0 = sp*1024;
    int sw  = (cc&7)<<4;            // phi read swizzle (256B rows)
    int sw2 = ((cc>>1)&3)<<4;       // gt/pa read swizzle (64B rows)

    __shared__ __align__(16) char ldsb[40960];
    char* phL = ldsb;               // [2][8192] phi tiles [32 keys][256B], XOR-swizzled
    char* gtL = ldsb + 16384;       // [2][8192] gt tiles [128 o][64B], XOR-swizzled
    char* plw = ldsb + 32768 + wv*2048;  // per-wave P [32 rows][64B], XOR-swizzled

    f16x8 aq[2][4];
    #pragma unroll
    for (int rb=0;rb<2;rb++){
        const f16* thp = th + ((size_t)(b*NN + qrow0 + rb*16 + cc))*CI + q*8;
        #pragma unroll
        for (int kk=0;kk<4;kk++) aq[rb][kk] = *(const f16x8*)(thp + kk*32);
    }

    const char* phg = (const char*)(ph + (size_t)b*NN*CI);
    const char* gtg = (const char*)gt2 + (size_t)b*64*16384;

    f32x4 yacc[2][8];
    #pragma unroll
    for (int rb=0;rb<2;rb++)
        #pragma unroll
        for (int os=0;os<8;os++) yacc[rb][os]=(f32x4){0,0,0,0};
    float m_run[2][4];
    f32x4 l_vec[2];
    #pragma unroll
    for (int rb=0;rb<2;rb++){
        l_vec[rb]=(f32x4){0,0,0,0};
        #pragma unroll
        for (int r=0;r<4;r++) m_run[rb][r]=-1e30f;
    }

    // staging: 32-key tile tt -> buffer bb. LDS dest linear; global source pre-swizzled.
    auto STAGE = [&](int tt, int bb){
        int key0 = kv0 + tt*32;
        int mt  = key0 >> 6;
        int kob = (key0 & 32)*2;       // byte offset of 32-key half within gt2 tile row
        char* pbase = phL + bb*8192 + wv*2048;
        char* gbase = gtL + bb*8192 + wv*2048;
        #pragma unroll
        for (int ch=0; ch<2; ch++){
            int prow = wv*8 + ch*4 + (lane>>4);
            const char* ps = phg + (size_t)(key0 + prow)*256 + (((lane&15)*16) ^ ((prow&7)<<4));
            __builtin_amdgcn_global_load_lds(GL1(ps), LDS3(pbase + ch*1024), 16, 0, 0);
            int gf = wv*2048 + ch*1024 + lane*16;
            int grow = gf>>6, gcol = gf&63;
            const char* gs = gtg + (size_t)mt*16384 + grow*128 + kob + (gcol ^ (((grow>>1)&3)<<4));
            __builtin_amdgcn_global_load_lds(GL1(gs), LDS3(gbase + ch*1024), 16, 0, 0);
        }
    };

    STAGE(0, 0);
    __syncthreads();

    int cur = 0;
    #pragma unroll 1
    for (int it=0; it<32; ++it){
        if (it < 31) STAGE(it+1, cur^1);
        const char* pt  = phL + cur*8192;
        const char* gtt = gtL + cur*8192;
        // QK^T: 2 key-groups of 16
        f32x4 fa[2][2];
        #pragma unroll
        for (int j=0;j<2;j++){
            f16x8 pf[4];
            #pragma unroll
            for (int kk=0;kk<4;kk++)
                pf[kk] = *(const f16x8*)(pt + (j*16+cc)*256 + ((kk*64 + q*16) ^ sw));
            fa[0][j]=(f32x4){0,0,0,0}; fa[1][j]=(f32x4){0,0,0,0};
            #pragma unroll
            for (int kk=0;kk<4;kk++){
                fa[0][j]=MFMA(aq[0][kk], pf[kk], fa[0][j]);
                fa[1][j]=MFMA(aq[1][kk], pf[kk], fa[1][j]);
            }
        }
        // tile max per row via DPP; defer-max skip (THR=3)
        float mx[2][4]; float need = 0.f;
        #pragma unroll
        for (int rb=0;rb<2;rb++){
            #pragma unroll
            for (int r=0;r<4;r++){
                float m0 = fmaxf(fa[rb][0][r],fa[rb][1][r]);
                m0 = rowmax16(m0);
                mx[rb][r]=m0;
                need = fmaxf(need, m0 - m_run[rb][r]);
            }
        }
        if (__any(need > 3.f)){
            #pragma unroll
            for (int rb=0;rb<2;rb++){
                #pragma unroll
                for (int r=0;r<4;r++){
                    float nm = fmaxf(m_run[rb][r], mx[rb][r]);
                    float co = __expf(m_run[rb][r]-nm);
                    m_run[rb][r]=nm;
                    l_vec[rb][r]*=co;
                    #pragma unroll
                    for (int os=0;os<8;os++) yacc[rb][os][r]*=co;
                }
            }
        }
        #pragma unroll
        for (int rb=0;rb<2;rb++){
            #pragma unroll
            for (int j=0;j<2;j++){
                #pragma unroll
                for (int r=0;r<4;r++) fa[rb][j][r]=__expf(fa[rb][j][r]-m_run[rb][r]);
            }
            #pragma unroll
            for (int r=0;r<4;r++)
                l_vec[rb][r] += fa[rb][0][r]+fa[rb][1][r];
        }
        // P scatter -> per-wave swizzled LDS [row=rb*16+4q+r][32 keys, 64B rows]
        #pragma unroll
        for (int rb=0;rb<2;rb++){
            #pragma unroll
            for (int j=0;j<2;j++){
                #pragma unroll
                for (int r=0;r<4;r++){
                    int swp = (((2*q) + (r>>1))&3)<<4;
                    *(f16*)(plw + (rb*16+4*q+r)*64 + (((j*16+cc)*2) ^ swp)) = (f16)fa[rb][j][r];
                }
            }
        }
        // PV: single K=32 step
        {
            f16x8 pa0 = *(const f16x8*)(plw +  cc     *64 + ((q*16) ^ sw2));
            f16x8 pa1 = *(const f16x8*)(plw + (16+cc) *64 + ((q*16) ^ sw2));
            #pragma unroll
            for (int os=0;os<8;os++){
                f16x8 gv = *(const f16x8*)(gtt + (os*16+cc)*64 + ((q*16) ^ sw2));
                yacc[0][os] = MFMA(pa0, gv, yacc[0][os]);
                yacc[1][os] = MFMA(pa1, gv, yacc[1][os]);
            }
        }
        __syncthreads();
        cur ^= 1;
    }
    // reduce l across 16 lanes; write NORMALIZED partials + (m,l)
    float linv[2][4], lred[2][4];
    #pragma unroll
    for (int rb=0;rb<2;rb++)
        #pragma unroll
        for (int r=0;r<4;r++){
            float l = rowsum16(l_vec[rb][r]);
            lred[rb][r]=l; linv[rb][r]=1.f/l;
        }
    #pragma unroll
    for (int rb=0;rb<2;rb++){
        #pragma unroll
        for (int os=0;os<8;os++){
            #pragma unroll
            for (int r=0;r<4;r++)
                ypart[((size_t)((sp*4+b)*NN + qrow0 + rb*16 + 4*q + r))*CI + os*16 + cc] = (f16)(yacc[rb][os][r]*linv[rb][r]);
        }
    }
    if (cc==0){
        #pragma unroll
        for (int rb=0;rb<2;rb++){
            #pragma unroll
            for (int r=0;r<4;r++){
                size_t row = (size_t)(sp*4+b)*NN + qrow0 + rb*16 + 4*q + r;
                ml[row*2]   = m_run[rb][r];
                ml[row*2+1] = lred[rb][r];
            }
        }
    }
}

// ---------------- K3c: fused combine + Gram/mean stats (MFMA), 64 rows/block, 256 blocks ----------------
__global__ __launch_bounds__(256) void k3c(const f16* ypart, const float* ml,
                                           f16* y, float* part, float* mupart){
    int blk = blockIdx.x; int t = threadIdx.x;     // 256 blocks
    int rloc = t>>2;                   // 0..63
    int row  = blk*64 + rloc;
    int b = row>>12, n = row & 4095;
    int o0 = (t&3)*32;
    __shared__ __align__(16) f16 ldsT[128*64];     // [o][n'] n-swizzled
    float m_s[4], l_s[4];
    #pragma unroll
    for (int s=0;s<4;s++){ size_t r2 = ((size_t)(s*4+b)*NN + n)*2; m_s[s]=ml[r2]; l_s[s]=ml[r2+1]; }
    float M = fmaxf(fmaxf(m_s[0],m_s[1]),fmaxf(m_s[2],m_s[3]));
    float w[4]; float L=0.f;
    #pragma unroll
    for (int s=0;s<4;s++){ w[s]=l_s[s]*__expf(m_s[s]-M); L+=w[s]; }
    float inv = 1.f/L;
    #pragma unroll
    for (int s=0;s<4;s++) w[s]*=inv;
    float acc[32];
    #pragma unroll
    for (int j=0;j<32;j++) acc[j]=0.f;
    #pragma unroll
    for (int s=0;s<4;s++){
        const f16* src = ypart + ((size_t)(s*4+b)*NN + n)*CI + o0;
        #pragma unroll
        for (int v=0;v<4;v++){
            f16x8 vv = *(const f16x8*)(src + v*8);
            #pragma unroll
            for (int e=0;e<8;e++) acc[v*8+e] += w[s]*(float)vv[e];
        }
    }
    f16* yo = y + (size_t)row*CI + o0;
    #pragma unroll
    for (int v=0;v<4;v++){
        f16x8 ov;
        #pragma unroll
        for (int e=0;e<8;e++) ov[e] = (f16)acc[v*8+e];
        *(f16x8*)(yo + v*8) = ov;
        #pragma unroll
        for (int e=0;e<8;e++){
            int o = o0 + v*8 + e;
            ldsT[o*64 + (rloc ^ ((o&7)<<3))] = ov[e];
        }
    }
    __syncthreads();
    // Gram partial via MFMA over 64 rows
    int wv=t>>6, lane=t&63, q=lane>>4, cc=lane&15;
    f32x4 gacc[2][8];
    #pragma unroll
    for (int a=0;a<2;a++)
        #pragma unroll
        for (int c2=0;c2<8;c2++) gacc[a][c2]=(f32x4){0,0,0,0};
    f16x8 af[2][2];
    #pragma unroll
    for (int o1t=0;o1t<2;o1t++){
        int o1 = (wv*2+o1t)*16+cc;
        #pragma unroll
        for (int kk=0;kk<2;kk++)
            af[o1t][kk] = *(const f16x8*)(ldsT + o1*64 + ((kk*32+q*8) ^ ((o1&7)<<3)));
    }
    #pragma unroll 1
    for (int o2t=0;o2t<8;o2t++){
        int o2 = o2t*16+cc;
        #pragma unroll
        for (int kk=0;kk<2;kk++){
            f16x8 bf = *(const f16x8*)(ldsT + o2*64 + ((kk*32+q*8) ^ ((o2&7)<<3)));
            gacc[0][o2t] = MFMA(af[0][kk], bf, gacc[0][o2t]);
            gacc[1][o2t] = MFMA(af[1][kk], bf, gacc[1][o2t]);
        }
    }
    float* pb = part + (size_t)blk*16384;
    #pragma unroll
    for (int o1t=0;o1t<2;o1t++){
        #pragma unroll
        for (int o2t=0;o2t<8;o2t++){
            #pragma unroll
            for (int r=0;r<4;r++)
                pb[((wv*2+o1t)*16+4*q+r)*128 + o2t*16+cc] = gacc[o1t][o2t][r];
        }
    }
    // mean partial
    if (t<128){
        float sm=0.f;
        #pragma unroll
        for (int v=0;v<8;v++){
            f16x8 vv = *(const f16x8*)(ldsT + t*64 + ((v*8) ^ ((t&7)<<3)));
            #pragma unroll
            for (int e=0;e<8;e++) sm += (float)vv[e];
        }
        mupart[blk*128 + t] = sm;
    }
}

// ---------------- K4b: chunked reduce of partials -> atomicAdd into S (pre-zeroed) ----------------
__global__ __launch_bounds__(256) void k4b_red(const float* part, const float* mupart, float* S){
    int pc = blockIdx.y;               // 8 chunks of 32 partials
    int t = threadIdx.x;
    if (blockIdx.x < 64){
        int i = blockIdx.x*256 + t;
        float s=0.f;
        #pragma unroll 1
        for (int p=pc*32; p<pc*32+32; p++) s += part[(size_t)p*16384 + i];
        atomicAdd(&S[i], s);
    } else if (t < 128){
        float s=0.f;
        #pragma unroll 1
        for (int p=pc*32; p<pc*32+32; p++) s += mupart[p*128 + t];
        atomicAdd(&S[16384+t], s);
    }
}

// ---------------- K4c: BN coefficients A[ch], B4[ch] ----------------
__global__ __launch_bounds__(128) void k4c_coef(const float* S, const float* Ww, const float* Wb,
                                                const float* gamma, const float* beta,
                                                const float* scale, float* AB){
    int ch = blockIdx.x; int t = threadIdx.x;
    const float* w = Ww + ch*CI;
    float tmp=0.f;
    const float* Srow = S + t*CI;
    #pragma unroll 1
    for (int o2=0;o2<CI;o2++) tmp += Srow[o2]*w[o2];
    float v  = w[t]*tmp;
    float mc = w[t]*S[16384 + t];
    #pragma unroll
    for (int s=1;s<64;s<<=1){ v += __shfl_xor(v,s); mc += __shfl_xor(mc,s); }
    __shared__ float red[4];
    if ((t&63)==0){ red[(t>>6)*2]=v; red[(t>>6)*2+1]=mc; }
    __syncthreads();
    if (t==0){
        float wSw = red[0]+red[2];
        float wmu = red[1]+red[3];
        const float M = 16384.f;
        float meanwy = wmu/M + Wb[ch];
        float var = wSw/M - (wmu/M)*(wmu/M);
        float inv = rsqrtf(var + 1e-5f);
        float sc = scale[0];
        float A  = sc*gamma[ch]*inv;
        float B3 = sc*(beta[ch] - meanwy*inv*gamma[ch]);
        AB[ch]     = A;
        AB[256+ch] = B3 + A*Wb[ch];
    }
}

// ---------------- K5: fused W-conv + BN + scale + residual, 512 blocks ----------------
__global__ __launch_bounds__(256) void k5_out(const f16* Wwh, const f16* y, const float* x,
                                              const float* AB, float* out){
    int ntile = blockIdx.x;      // 32
    int cht   = blockIdx.y;      // 4
    int b     = blockIdx.z;
    int wv=threadIdx.x>>6, lane=threadIdx.x&63, q=lane>>4, cc=lane&15;
    int ch0 = cht*64 + wv*16;
    f16x8 aw[4];
    const f16* wp = Wwh + ((size_t)(ch0+cc))*CI + q*8;
    #pragma unroll
    for (int kk=0;kk<4;kk++) aw[kk]=*(const f16x8*)(wp+kk*32);
    float Ar[4], Br[4];
    #pragma unroll
    for (int r=0;r<4;r++){ Ar[r]=AB[ch0+4*q+r]; Br[r]=AB[256+ch0+4*q+r]; }
    #pragma unroll 1
    for (int ns=0;ns<8;ns++){
        int n0 = ntile*128 + ns*16;
        f32x4 acc={0,0,0,0};
        const f16* yp = y + ((size_t)(b*NN + n0 + cc))*CI + q*8;
        #pragma unroll
        for (int kk=0;kk<4;kk++) acc = MFMA(aw[kk], *(const f16x8*)(yp+kk*32), acc);
        #pragma unroll
        for (int r=0;r<4;r++){
            size_t addr = ((size_t)(b*CC + ch0 + 4*q + r))*NN + n0 + cc;
            out[addr] = x[addr] + Ar[r]*acc[r] + Br[r];
        }
    }
}

extern "C" void kernel_launch(void* const* d_in, const int* in_sizes, int n_in,
                              void* d_out, int out_size, void* d_ws, size_t ws_size,
                              hipStream_t stream){
    const float* x    = (const float*)d_in[0];
    const float* g_w  = (const float*)d_in[1];
    const float* g_b  = (const float*)d_in[2];
    const float* th_w = (const float*)d_in[3];
    const float* th_b = (const float*)d_in[4];
    const float* ph_w = (const float*)d_in[5];
    const float* ph_b = (const float*)d_in[6];
    const float* W_w  = (const float*)d_in[7];
    const float* W_b  = (const float*)d_in[8];
    const float* bg   = (const float*)d_in[9];
    const float* bb   = (const float*)d_in[10];
    const float* sc   = (const float*)d_in[11];

    char* ws = (char*)d_ws;
    f16* xt  = (f16*)(ws);                                  // 8.4 MB
    f16* th  = (f16*)(ws + 8388608);                        // 4.2 MB
    f16* ph  = (f16*)(ws + 8388608 + 1*4194304);            // 4.2 MB
    f16* gt2 = (f16*)(ws + 8388608 + 2*4194304);            // 4.2 MB (tiled [b][mt][128][64])
    f16* y   = (f16*)(ws + 8388608 + 3*4194304);            // 4.2 MB
    f16* wh  = (f16*)(ws + 8388608 + 4*4194304);            // 256 KB
    float* ml    = (float*)(ws + 25427968);                 // 512 KB
    f16*   ypart = (f16*)(ws + 25952256);                   // 16.8 MB
    float* mupart= (float*)(ws + 42729472);                 // 128 KB
    float* part  = (float*)ws;                              // 16.8 MB overlay on xt+th+ph (dead after k3)
    float* S    = (float*)(ws + 42860544);                  // 66 KB
    float* AB   = (float*)(ws + 42926592);                  // 2 KB
    f16* th_wh = wh;
    f16* ph_wh = wh + 32768;
    f16* g_wh  = wh + 65536;
    f16* Ww_h  = wh + 98304;

    hipMemsetAsync(S, 0, 16512*sizeof(float), stream);
    hipLaunchKernelGGL(k01_xpose, dim3(64,4,4), dim3(256), 0, stream, x, xt, th_w, ph_w, g_w, W_w, wh);
    hipLaunchKernelGGL(k2_all,   dim3(128,4),   dim3(256), 0, stream, xt, th_wh, ph_wh, g_wh,
                       th_b, ph_b, g_b, th, ph, gt2);
    hipLaunchKernelGGL(k3_attn,  dim3(32,4,4),  dim3(256), 0, stream, th, ph, gt2, ypart, ml);
    hipLaunchKernelGGL(k3c,      dim3(256),     dim3(256), 0, stream, ypart, ml, y, part, mupart);
    hipLaunchKernelGGL(k4b_red,  dim3(65,8),    dim3(256), 0, stream, part, mupart, S);
    hipLaunchKernelGGL(k4c_coef, dim3(256),     dim3(128), 0, stream, S, W_w, W_b, bg, bb, sc, AB);
    hipLaunchKernelGGL(k5_out,   dim3(32,4,4),  dim3(256), 0, stream, Ww_h, y, x, AB, (float*)d_out);
}

// Round 9
// 162.815 us; speedup vs baseline: 1.0394x; 1.0394x over previous
//
#include <hip/hip_runtime.h>
#include <hip/hip_bf16.h>

#define BB 4
#define CC 256
#define CI 128
#define NN 4096

typedef _Float16 f16;
typedef __attribute__((ext_vector_type(8))) _Float16 f16x8;
typedef __attribute__((ext_vector_type(4))) float f32x4;

#define MFMA(a,b,c) __builtin_amdgcn_mfma_f32_16x16x32_f16(a,b,c,0,0,0)
#define LDS3(p) ((__attribute__((address_space(3))) void*)(p))
#define GL1(p)  ((const __attribute__((address_space(1))) void*)(p))

// DPP 16-lane butterfly reduce (1-cy VALU ops, no LDS pipe)
#define DPP_MAX(x, ctrl) { int _s=__float_as_int(x); \
    float _y=__int_as_float(__builtin_amdgcn_update_dpp(_s,_s,ctrl,0xF,0xF,false)); \
    x = fmaxf(x,_y); }
#define DPP_ADD(x, ctrl) { int _s=__float_as_int(x); \
    float _y=__int_as_float(__builtin_amdgcn_update_dpp(_s,_s,ctrl,0xF,0xF,false)); \
    x = x+_y; }
__device__ __forceinline__ float rowmax16(float x){
    DPP_MAX(x,0xB1) DPP_MAX(x,0x4E) DPP_MAX(x,0x141) DPP_MAX(x,0x140) return x;
}
__device__ __forceinline__ float rowsum16(float x){
    DPP_ADD(x,0xB1) DPP_ADD(x,0x4E) DPP_ADD(x,0x141) DPP_ADD(x,0x140) return x;
}

// ---------------- K01: transpose+cast x -> xt, plus weight cast (fused k0) ----------------
__global__ __launch_bounds__(256) void k01_xpose(const float* x, f16* xt,
                                                 const float* tw, const float* pw,
                                                 const float* gw, const float* Ww, f16* wdst){
    int nt = blockIdx.x, ct = blockIdx.y, b = blockIdx.z;
    __shared__ float tile[64][65];
    int t = threadIdx.x;
    const float* src = x + ((size_t)(b*CC + ct*64))*NN + nt*64;
    #pragma unroll
    for (int k=0;k<16;k++){ int idx=t+k*256; int cl=idx>>6, nl=idx&63;
        tile[cl][nl]=src[(size_t)cl*NN + nl]; }
    __syncthreads();
    f16* dst = xt + ((size_t)(b*NN + nt*64))*CC + ct*64;
    #pragma unroll
    for (int k=0;k<16;k++){ int idx=t+k*256; int nl=idx>>6, cl=idx&63;
        dst[(size_t)nl*CC + cl] = (f16)tile[cl][nl]; }
    // fused weight cast: 1024 blocks x 128 elements = 131072
    if (t < 128){
        int blkId = blockIdx.x + 64*(blockIdx.y + 4*blockIdx.z);
        int i = blkId*128 + t;
        int j = i & 32767; int sel = i >> 15;
        const float* s = (sel==0)? tw : (sel==1)? pw : (sel==2)? gw : Ww;
        wdst[i] = (f16)s[j];
    }
}

// ---------------- K2: merged theta/phi/g projections, 512 blocks ----------------
__global__ __launch_bounds__(256) void k2_all(const f16* xt, const f16* thw, const f16* phw,
                                              const f16* gwh, const float* thb, const float* phb,
                                              const float* gb, f16* th, f16* ph, f16* gt2){
    int b = blockIdx.y; int xx = blockIdx.x;
    int wv = threadIdx.x>>6, lane = threadIdx.x&63, q=lane>>4, cc=lane&15;
    if (xx < 64){
        // theta (xx<32) or phi (xx>=32), 128 rows per block
        int mat = xx>>5; int ntile = xx&31;
        int n0 = ntile*128 + wv*32;
        f16x8 aq[2][8];
        #pragma unroll
        for (int ns=0;ns<2;ns++){
            const f16* ap = xt + ((size_t)(b*NN + n0 + ns*16 + cc))*CC + q*8;
            #pragma unroll
            for (int kk=0;kk<8;kk++) aq[ns][kk] = *(const f16x8*)(ap + kk*32);
        }
        const f16* w   = mat? phw : thw;
        const float* bias = mat? phb : thb;
        f16* o = mat? ph : th;
        #pragma unroll 1
        for (int os=0;os<8;os++){
            f32x4 acc0={0,0,0,0}, acc1={0,0,0,0};
            const f16* wp = w + ((size_t)(os*16 + cc))*CC + q*8;
            #pragma unroll
            for (int kk=0;kk<8;kk++){
                f16x8 bf = *(const f16x8*)(wp + kk*32);
                acc0 = MFMA(aq[0][kk], bf, acc0);
                acc1 = MFMA(aq[1][kk], bf, acc1);
            }
            float bv = bias[os*16+cc];
            #pragma unroll
            for (int r=0;r<4;r++){
                o[((size_t)(b*NN + n0      + 4*q + r))*CI + os*16 + cc] = (f16)(acc0[r] + bv);
                o[((size_t)(b*NN + n0 + 16 + 4*q + r))*CI + os*16 + cc] = (f16)(acc1[r] + bv);
            }
        }
    } else {
        // g projection, TILED output gt2[b][mt][o][64]
        int mt = xx - 64;
        f16x8 ag[2][8];
        #pragma unroll
        for (int os=0;os<2;os++){
            const f16* ap = gwh + ((size_t)(wv*32 + os*16 + cc))*CC + q*8;
            #pragma unroll
            for (int kk=0;kk<8;kk++) ag[os][kk] = *(const f16x8*)(ap + kk*32);
        }
        f32x4 acc[2][4];
        #pragma unroll
        for (int os=0;os<2;os++){
            #pragma unroll
            for (int ms=0;ms<4;ms++) acc[os][ms]=(f32x4){0,0,0,0};
        }
        #pragma unroll 1
        for (int kk=0;kk<8;kk++){
            #pragma unroll
            for (int ms=0;ms<4;ms++){
                f16x8 bf = *(const f16x8*)(xt + ((size_t)(b*NN + mt*64 + ms*16 + cc))*CC + kk*32 + q*8);
                acc[0][ms]=MFMA(ag[0][kk],bf,acc[0][ms]);
                acc[1][ms]=MFMA(ag[1][kk],bf,acc[1][ms]);
            }
        }
        #pragma unroll
        for (int os=0;os<2;os++){
            #pragma unroll
            for (int r=0;r<4;r++){
                int orow = wv*32 + os*16 + 4*q + r;
                float bv = gb[orow];
                #pragma unroll
                for (int ms=0;ms<4;ms++)
                    gt2[((size_t)(b*64 + mt))*8192 + orow*64 + ms*16 + cc] = (f16)(acc[os][ms][r] + bv);
            }
        }
    }
}

// ---------------- K3: flash attention, KVBLK=32, 64 q-rows/block, 36KB LDS, 1024 blocks ----------------
__global__ __launch_bounds__(256, 4) void k3_attn(const f16* th, const f16* ph, const f16* gt2,
                                                  f16* ypart, float* ml){
    int qt = blockIdx.x;           // 64 q-tiles of 64 rows
    int sp = blockIdx.y;           // 4 key splits of 1024 keys
    int b  = blockIdx.z;           // 4 batches
    int wv=threadIdx.x>>6, lane=threadIdx.x&63, q=lane>>4, cc=lane&15;
    int qrow0 = qt*64 + wv*16;
    int kv0 = sp*1024;
    int sw  = (cc&7)<<4;            // phi read swizzle (256B rows)
    int sw2 = ((cc>>1)&3)<<4;       // gt/pa read swizzle (64B rows)

    __shared__ __align__(16) char ldsb[36864];
    char* phL = ldsb;               // [2][8192] phi tiles [32 keys][256B], XOR-swizzled
    char* gtL = ldsb + 16384;       // [2][8192] gt tiles [128 o][64B], XOR-swizzled
    char* plw = ldsb + 32768 + wv*1024;  // per-wave P [16 rows][64B], XOR-swizzled

    f16x8 aq[4];
    const f16* thp = th + ((size_t)(b*NN + qrow0 + cc))*CI + q*8;
    #pragma unroll
    for (int kk=0;kk<4;kk++) aq[kk] = *(const f16x8*)(thp + kk*32);

    const char* phg = (const char*)(ph + (size_t)b*NN*CI);
    const char* gtg = (const char*)gt2 + (size_t)b*64*16384;

    f32x4 yacc[8];
    #pragma unroll
    for (int os=0;os<8;os++) yacc[os]=(f32x4){0,0,0,0};
    float m_run[4];
    f32x4 l_vec=(f32x4){0,0,0,0};
    #pragma unroll
    for (int r=0;r<4;r++) m_run[r]=-1e30f;

    // staging: 32-key tile tt -> buffer bb. LDS dest linear; global source pre-swizzled.
    auto STAGE = [&](int tt, int bb){
        int key0 = kv0 + tt*32;
        int mt  = key0 >> 6;
        int kob = (key0 & 32)*2;       // byte offset of 32-key half within gt2 tile row
        char* pbase = phL + bb*8192 + wv*2048;
        char* gbase = gtL + bb*8192 + wv*2048;
        #pragma unroll
        for (int ch=0; ch<2; ch++){
            int prow = wv*8 + ch*4 + (lane>>4);
            const char* ps = phg + (size_t)(key0 + prow)*256 + (((lane&15)*16) ^ ((prow&7)<<4));
            __builtin_amdgcn_global_load_lds(GL1(ps), LDS3(pbase + ch*1024), 16, 0, 0);
            int gf = wv*2048 + ch*1024 + lane*16;
            int grow = gf>>6, gcol = gf&63;
            const char* gs = gtg + (size_t)mt*16384 + grow*128 + kob + (gcol ^ (((grow>>1)&3)<<4));
            __builtin_amdgcn_global_load_lds(GL1(gs), LDS3(gbase + ch*1024), 16, 0, 0);
        }
    };

    STAGE(0, 0);
    __syncthreads();

    int cur = 0;
    #pragma unroll 1
    for (int it=0; it<32; ++it){
        if (it < 31) STAGE(it+1, cur^1);
        const char* pt  = phL + cur*8192;
        const char* gtt = gtL + cur*8192;
        // QK^T: 2 key-groups of 16
        f32x4 fa[2];
        #pragma unroll
        for (int j=0;j<2;j++){
            f16x8 pf[4];
            #pragma unroll
            for (int kk=0;kk<4;kk++)
                pf[kk] = *(const f16x8*)(pt + (j*16+cc)*256 + ((kk*64 + q*16) ^ sw));
            fa[j]=(f32x4){0,0,0,0};
            #pragma unroll
            for (int kk=0;kk<4;kk++)
                fa[j]=MFMA(aq[kk], pf[kk], fa[j]);
        }
        // tile max per row via DPP; defer-max skip (THR=3)
        float mx[4]; float need = 0.f;
        #pragma unroll
        for (int r=0;r<4;r++){
            float m0 = fmaxf(fa[0][r],fa[1][r]);
            m0 = rowmax16(m0);
            mx[r]=m0;
            need = fmaxf(need, m0 - m_run[r]);
        }
        if (__any(need > 3.f)){
            #pragma unroll
            for (int r=0;r<4;r++){
                float nm = fmaxf(m_run[r], mx[r]);
                float co = __expf(m_run[r]-nm);
                m_run[r]=nm;
                l_vec[r]*=co;
                #pragma unroll
                for (int os=0;os<8;os++) yacc[os][r]*=co;
            }
        }
        #pragma unroll
        for (int j=0;j<2;j++){
            #pragma unroll
            for (int r=0;r<4;r++) fa[j][r]=__expf(fa[j][r]-m_run[r]);
        }
        #pragma unroll
        for (int r=0;r<4;r++)
            l_vec[r] += fa[0][r]+fa[1][r];
        // P scatter -> per-wave swizzled LDS [row=4q+r][32 keys, 64B rows]
        #pragma unroll
        for (int j=0;j<2;j++){
            #pragma unroll
            for (int r=0;r<4;r++){
                int R = 4*q+r;
                *(f16*)(plw + R*64 + (((j*16+cc)*2) ^ (((R>>1)&3)<<4))) = (f16)fa[j][r];
            }
        }
        // PV: single K=32 step
        {
            f16x8 pa0 = *(const f16x8*)(plw + cc*64 + ((q*16) ^ sw2));
            #pragma unroll
            for (int os=0;os<8;os++){
                f16x8 gv = *(const f16x8*)(gtt + (os*16+cc)*64 + ((q*16) ^ sw2));
                yacc[os] = MFMA(pa0, gv, yacc[os]);
            }
        }
        __syncthreads();
        cur ^= 1;
    }
    // reduce l across 16 lanes; write NORMALIZED partials + (m,l)
    float linv[4], lred[4];
    #pragma unroll
    for (int r=0;r<4;r++){
        float l = rowsum16(l_vec[r]);
        lred[r]=l; linv[r]=1.f/l;
    }
    #pragma unroll
    for (int os=0;os<8;os++){
        #pragma unroll
        for (int r=0;r<4;r++)
            ypart[((size_t)((sp*4+b)*NN + qrow0 + 4*q + r))*CI + os*16 + cc] = (f16)(yacc[os][r]*linv[r]);
    }
    if (cc==0){
        #pragma unroll
        for (int r=0;r<4;r++){
            size_t row = (size_t)(sp*4+b)*NN + qrow0 + 4*q + r;
            ml[row*2]   = m_run[r];
            ml[row*2+1] = lred[r];
        }
    }
}

// ---------------- K3c: fused combine + Gram/mean stats (MFMA), 64 rows/block, 256 blocks ----------------
__global__ __launch_bounds__(256) void k3c(const f16* ypart, const float* ml,
                                           f16* y, float* part, float* mupart){
    int blk = blockIdx.x; int t = threadIdx.x;     // 256 blocks
    int rloc = t>>2;                   // 0..63
    int row  = blk*64 + rloc;
    int b = row>>12, n = row & 4095;
    int o0 = (t&3)*32;
    __shared__ __align__(16) f16 ldsT[128*64];     // [o][n'] n-swizzled
    float m_s[4], l_s[4];
    #pragma unroll
    for (int s=0;s<4;s++){ size_t r2 = ((size_t)(s*4+b)*NN + n)*2; m_s[s]=ml[r2]; l_s[s]=ml[r2+1]; }
    float M = fmaxf(fmaxf(m_s[0],m_s[1]),fmaxf(m_s[2],m_s[3]));
    float w[4]; float L=0.f;
    #pragma unroll
    for (int s=0;s<4;s++){ w[s]=l_s[s]*__expf(m_s[s]-M); L+=w[s]; }
    float inv = 1.f/L;
    #pragma unroll
    for (int s=0;s<4;s++) w[s]*=inv;
    float acc[32];
    #pragma unroll
    for (int j=0;j<32;j++) acc[j]=0.f;
    #pragma unroll
    for (int s=0;s<4;s++){
        const f16* src = ypart + ((size_t)(s*4+b)*NN + n)*CI + o0;
        #pragma unroll
        for (int v=0;v<4;v++){
            f16x8 vv = *(const f16x8*)(src + v*8);
            #pragma unroll
            for (int e=0;e<8;e++) acc[v*8+e] += w[s]*(float)vv[e];
        }
    }
    f16* yo = y + (size_t)row*CI + o0;
    #pragma unroll
    for (int v=0;v<4;v++){
        f16x8 ov;
        #pragma unroll
        for (int e=0;e<8;e++) ov[e] = (f16)acc[v*8+e];
        *(f16x8*)(yo + v*8) = ov;
        #pragma unroll
        for (int e=0;e<8;e++){
            int o = o0 + v*8 + e;
            ldsT[o*64 + (rloc ^ ((o&7)<<3))] = ov[e];
        }
    }
    __syncthreads();
    // Gram partial via MFMA over 64 rows
    int wv=t>>6, lane=t&63, q=lane>>4, cc=lane&15;
    f32x4 gacc[2][8];
    #pragma unroll
    for (int a=0;a<2;a++)
        #pragma unroll
        for (int c2=0;c2<8;c2++) gacc[a][c2]=(f32x4){0,0,0,0};
    f16x8 af[2][2];
    #pragma unroll
    for (int o1t=0;o1t<2;o1t++){
        int o1 = (wv*2+o1t)*16+cc;
        #pragma unroll
        for (int kk=0;kk<2;kk++)
            af[o1t][kk] = *(const f16x8*)(ldsT + o1*64 + ((kk*32+q*8) ^ ((o1&7)<<3)));
    }
    #pragma unroll 1
    for (int o2t=0;o2t<8;o2t++){
        int o2 = o2t*16+cc;
        #pragma unroll
        for (int kk=0;kk<2;kk++){
            f16x8 bf = *(const f16x8*)(ldsT + o2*64 + ((kk*32+q*8) ^ ((o2&7)<<3)));
            gacc[0][o2t] = MFMA(af[0][kk], bf, gacc[0][o2t]);
            gacc[1][o2t] = MFMA(af[1][kk], bf, gacc[1][o2t]);
        }
    }
    float* pb = part + (size_t)blk*16384;
    #pragma unroll
    for (int o1t=0;o1t<2;o1t++){
        #pragma unroll
        for (int o2t=0;o2t<8;o2t++){
            #pragma unroll
            for (int r=0;r<4;r++)
                pb[((wv*2+o1t)*16+4*q+r)*128 + o2t*16+cc] = gacc[o1t][o2t][r];
        }
    }
    // mean partial
    if (t<128){
        float sm=0.f;
        #pragma unroll
        for (int v=0;v<8;v++){
            f16x8 vv = *(const f16x8*)(ldsT + t*64 + ((v*8) ^ ((t&7)<<3)));
            #pragma unroll
            for (int e=0;e<8;e++) sm += (float)vv[e];
        }
        mupart[blk*128 + t] = sm;
    }
}

// ---------------- K4b: chunked reduce of partials -> atomicAdd into S (pre-zeroed) ----------------
__global__ __launch_bounds__(256) void k4b_red(const float* part, const float* mupart, float* S){
    int pc = blockIdx.y;               // 8 chunks of 32 partials
    int t = threadIdx.x;
    if (blockIdx.x < 64){
        int i = blockIdx.x*256 + t;
        float s=0.f;
        #pragma unroll 1
        for (int p=pc*32; p<pc*32+32; p++) s += part[(size_t)p*16384 + i];
        atomicAdd(&S[i], s);
    } else if (t < 128){
        float s=0.f;
        #pragma unroll 1
        for (int p=pc*32; p<pc*32+32; p++) s += mupart[p*128 + t];
        atomicAdd(&S[16384+t], s);
    }
}

// ---------------- K4c: BN coefficients A[ch], B4[ch] ----------------
__global__ __launch_bounds__(128) void k4c_coef(const float* S, const float* Ww, const float* Wb,
                                                const float* gamma, const float* beta,
                                                const float* scale, float* AB){
    int ch = blockIdx.x; int t = threadIdx.x;
    const float* w = Ww + ch*CI;
    float tmp=0.f;
    const float* Srow = S + t*CI;
    #pragma unroll 1
    for (int o2=0;o2<CI;o2++) tmp += Srow[o2]*w[o2];
    float v  = w[t]*tmp;
    float mc = w[t]*S[16384 + t];
    #pragma unroll
    for (int s=1;s<64;s<<=1){ v += __shfl_xor(v,s); mc += __shfl_xor(mc,s); }
    __shared__ float red[4];
    if ((t&63)==0){ red[(t>>6)*2]=v; red[(t>>6)*2+1]=mc; }
    __syncthreads();
    if (t==0){
        float wSw = red[0]+red[2];
        float wmu = red[1]+red[3];
        const float M = 16384.f;
        float meanwy = wmu/M + Wb[ch];
        float var = wSw/M - (wmu/M)*(wmu/M);
        float inv = rsqrtf(var + 1e-5f);
        float sc = scale[0];
        float A  = sc*gamma[ch]*inv;
        float B3 = sc*(beta[ch] - meanwy*inv*gamma[ch]);
        AB[ch]     = A;
        AB[256+ch] = B3 + A*Wb[ch];
    }
}

// ---------------- K5: fused W-conv + BN + scale + residual, 512 blocks ----------------
__global__ __launch_bounds__(256) void k5_out(const f16* Wwh, const f16* y, const float* x,
                                              const float* AB, float* out){
    int ntile = blockIdx.x;      // 32
    int cht   = blockIdx.y;      // 4
    int b     = blockIdx.z;
    int wv=threadIdx.x>>6, lane=threadIdx.x&63, q=lane>>4, cc=lane&15;
    int ch0 = cht*64 + wv*16;
    f16x8 aw[4];
    const f16* wp = Wwh + ((size_t)(ch0+cc))*CI + q*8;
    #pragma unroll
    for (int kk=0;kk<4;kk++) aw[kk]=*(const f16x8*)(wp+kk*32);
    float Ar[4], Br[4];
    #pragma unroll
    for (int r=0;r<4;r++){ Ar[r]=AB[ch0+4*q+r]; Br[r]=AB[256+ch0+4*q+r]; }
    #pragma unroll 1
    for (int ns=0;ns<8;ns++){
        int n0 = ntile*128 + ns*16;
        f32x4 acc={0,0,0,0};
        const f16* yp = y + ((size_t)(b*NN + n0 + cc))*CI + q*8;
        #pragma unroll
        for (int kk=0;kk<4;kk++) acc = MFMA(aw[kk], *(const f16x8*)(yp+kk*32), acc);
        #pragma unroll
        for (int r=0;r<4;r++){
            size_t addr = ((size_t)(b*CC + ch0 + 4*q + r))*NN + n0 + cc;
            out[addr] = x[addr] + Ar[r]*acc[r] + Br[r];
        }
    }
}

extern "C" void kernel_launch(void* const* d_in, const int* in_sizes, int n_in,
                              void* d_out, int out_size, void* d_ws, size_t ws_size,
                              hipStream_t stream){
    const float* x    = (const float*)d_in[0];
    const float* g_w  = (const float*)d_in[1];
    const float* g_b  = (const float*)d_in[2];
    const float* th_w = (const float*)d_in[3];
    const float* th_b = (const float*)d_in[4];
    const float* ph_w = (const float*)d_in[5];
    const float* ph_b = (const float*)d_in[6];
    const float* W_w  = (const float*)d_in[7];
    const float* W_b  = (const float*)d_in[8];
    const float* bg   = (const float*)d_in[9];
    const float* bb   = (const float*)d_in[10];
    const float* sc   = (const float*)d_in[11];

    char* ws = (char*)d_ws;
    f16* xt  = (f16*)(ws);                                  // 8.4 MB
    f16* th  = (f16*)(ws + 8388608);                        // 4.2 MB
    f16* ph  = (f16*)(ws + 8388608 + 1*4194304);            // 4.2 MB
    f16* gt2 = (f16*)(ws + 8388608 + 2*4194304);            // 4.2 MB (tiled [b][mt][128][64])
    f16* y   = (f16*)(ws + 8388608 + 3*4194304);            // 4.2 MB
    f16* wh  = (f16*)(ws + 8388608 + 4*4194304);            // 256 KB
    float* ml    = (float*)(ws + 25427968);                 // 512 KB
    f16*   ypart = (f16*)(ws + 25952256);                   // 16.8 MB
    float* mupart= (float*)(ws + 42729472);                 // 128 KB
    float* part  = (float*)ws;                              // 16.8 MB overlay on xt+th+ph (dead after k3)
    float* S    = (float*)(ws + 42860544);                  // 66 KB
    float* AB   = (float*)(ws + 42926592);                  // 2 KB
    f16* th_wh = wh;
    f16* ph_wh = wh + 32768;
    f16* g_wh  = wh + 65536;
    f16* Ww_h  = wh + 98304;

    hipMemsetAsync(S, 0, 16512*sizeof(float), stream);
    hipLaunchKernelGGL(k01_xpose, dim3(64,4,4), dim3(256), 0, stream, x, xt, th_w, ph_w, g_w, W_w, wh);
    hipLaunchKernelGGL(k2_all,   dim3(128,4),   dim3(256), 0, stream, xt, th_wh, ph_wh, g_wh,
                       th_b, ph_b, g_b, th, ph, gt2);
    hipLaunchKernelGGL(k3_attn,  dim3(64,4,4),  dim3(256), 0, stream, th, ph, gt2, ypart, ml);
    hipLaunchKernelGGL(k3c,      dim3(256),     dim3(256), 0, stream, ypart, ml, y, part, mupart);
    hipLaunchKernelGGL(k4b_red,  dim3(65,8),    dim3(256), 0, stream, part, mupart, S);
    hipLaunchKernelGGL(k4c_coef, dim3(256),     dim3(128), 0, stream, S, W_w, W_b, bg, bb, sc, AB);
    hipLaunchKernelGGL(k5_out,   dim3(32,4,4),  dim3(256), 0, stream, Ww_h, y, x, AB, (float*)d_out);
}

// Round 10
// 155.904 us; speedup vs baseline: 1.0855x; 1.0443x over previous
//
#include <hip/hip_runtime.h>
#include <hip/hip_bf16.h>

#define BB 4
#define CC 256
#define CI 128
#define NN 4096

typedef _Float16 f16;
typedef __attribute__((ext_vector_type(8))) _Float16 f16x8;
typedef __attribute__((ext_vector_type(4))) _Float16 f16x4;
typedef __attribute__((ext_vector_type(4))) float f32x4;

#define MFMA(a,b,c) __builtin_amdgcn_mfma_f32_16x16x32_f16(a,b,c,0,0,0)
#define LDS3(p) ((__attribute__((address_space(3))) void*)(p))
#define GL1(p)  ((const __attribute__((address_space(1))) void*)(p))

// ---------------- K01: transpose+cast x -> xt, plus weight cast (fused k0) ----------------
__global__ __launch_bounds__(256) void k01_xpose(const float* x, f16* xt,
                                                 const float* tw, const float* pw,
                                                 const float* gw, const float* Ww, f16* wdst){
    int nt = blockIdx.x, ct = blockIdx.y, b = blockIdx.z;
    __shared__ float tile[64][65];
    int t = threadIdx.x;
    const float* src = x + ((size_t)(b*CC + ct*64))*NN + nt*64;
    #pragma unroll
    for (int k=0;k<16;k++){ int idx=t+k*256; int cl=idx>>6, nl=idx&63;
        tile[cl][nl]=src[(size_t)cl*NN + nl]; }
    __syncthreads();
    f16* dst = xt + ((size_t)(b*NN + nt*64))*CC + ct*64;
    #pragma unroll
    for (int k=0;k<16;k++){ int idx=t+k*256; int nl=idx>>6, cl=idx&63;
        dst[(size_t)nl*CC + cl] = (f16)tile[cl][nl]; }
    // fused weight cast: 1024 blocks x 128 elements = 131072
    if (t < 128){
        int blkId = blockIdx.x + 64*(blockIdx.y + 4*blockIdx.z);
        int i = blkId*128 + t;
        int j = i & 32767; int sel = i >> 15;
        const float* s = (sel==0)? tw : (sel==1)? pw : (sel==2)? gw : Ww;
        wdst[i] = (f16)s[j];
    }
}

// ---------------- K2: merged theta/phi/g projections, 512 blocks ----------------
__global__ __launch_bounds__(256) void k2_all(const f16* xt, const f16* thw, const f16* phw,
                                              const f16* gwh, const float* thb, const float* phb,
                                              const float* gb, f16* th, f16* ph, f16* gt2){
    int b = blockIdx.y; int xx = blockIdx.x;
    int wv = threadIdx.x>>6, lane = threadIdx.x&63, q=lane>>4, cc=lane&15;
    if (xx < 64){
        // theta (xx<32) or phi (xx>=32), 128 rows per block
        int mat = xx>>5; int ntile = xx&31;
        int n0 = ntile*128 + wv*32;
        f16x8 aq[2][8];
        #pragma unroll
        for (int ns=0;ns<2;ns++){
            const f16* ap = xt + ((size_t)(b*NN + n0 + ns*16 + cc))*CC + q*8;
            #pragma unroll
            for (int kk=0;kk<8;kk++) aq[ns][kk] = *(const f16x8*)(ap + kk*32);
        }
        const f16* w   = mat? phw : thw;
        const float* bias = mat? phb : thb;
        f16* o = mat? ph : th;
        #pragma unroll 1
        for (int os=0;os<8;os++){
            f32x4 acc0={0,0,0,0}, acc1={0,0,0,0};
            const f16* wp = w + ((size_t)(os*16 + cc))*CC + q*8;
            #pragma unroll
            for (int kk=0;kk<8;kk++){
                f16x8 bf = *(const f16x8*)(wp + kk*32);
                acc0 = MFMA(aq[0][kk], bf, acc0);
                acc1 = MFMA(aq[1][kk], bf, acc1);
            }
            float bv = bias[os*16+cc];
            #pragma unroll
            for (int r=0;r<4;r++){
                o[((size_t)(b*NN + n0      + 4*q + r))*CI + os*16 + cc] = (f16)(acc0[r] + bv);
                o[((size_t)(b*NN + n0 + 16 + 4*q + r))*CI + os*16 + cc] = (f16)(acc1[r] + bv);
            }
        }
    } else {
        // g projection, TILED output gt2[b][mt][o][64]
        int mt = xx - 64;
        f16x8 ag[2][8];
        #pragma unroll
        for (int os=0;os<2;os++){
            const f16* ap = gwh + ((size_t)(wv*32 + os*16 + cc))*CC + q*8;
            #pragma unroll
            for (int kk=0;kk<8;kk++) ag[os][kk] = *(const f16x8*)(ap + kk*32);
        }
        f32x4 acc[2][4];
        #pragma unroll
        for (int os=0;os<2;os++){
            #pragma unroll
            for (int ms=0;ms<4;ms++) acc[os][ms]=(f32x4){0,0,0,0};
        }
        #pragma unroll 1
        for (int kk=0;kk<8;kk++){
            #pragma unroll
            for (int ms=0;ms<4;ms++){
                f16x8 bf = *(const f16x8*)(xt + ((size_t)(b*NN + mt*64 + ms*16 + cc))*CC + kk*32 + q*8);
                acc[0][ms]=MFMA(ag[0][kk],bf,acc[0][ms]);
                acc[1][ms]=MFMA(ag[1][kk],bf,acc[1][ms]);
            }
        }
        #pragma unroll
        for (int os=0;os<2;os++){
            #pragma unroll
            for (int r=0;r<4;r++){
                int orow = wv*32 + os*16 + 4*q + r;
                float bv = gb[orow];
                #pragma unroll
                for (int ms=0;ms<4;ms++)
                    gt2[((size_t)(b*64 + mt))*8192 + orow*64 + ms*16 + cc] = (f16)(acc[os][ms][r] + bv);
            }
        }
    }
}

// ---------------- K3: flash attention, swapped QK^T (P in registers), KVBLK=32, 32KB LDS ----------------
__global__ __launch_bounds__(256, 4) void k3_attn(const f16* th, const f16* ph, const f16* gt2,
                                                  f16* ypart, float* ml){
    int qt = blockIdx.x;           // 64 q-tiles of 64 rows
    int sp = blockIdx.y;           // 4 key splits of 1024 keys
    int b  = blockIdx.z;           // 4 batches
    int wv=threadIdx.x>>6, lane=threadIdx.x&63, q=lane>>4, cc=lane&15;
    int qrow0 = qt*64 + wv*16;
    int kv0 = sp*1024;
    int sw  = (cc&7)<<4;            // phi read swizzle (256B rows)
    int sw2 = ((cc>>1)&3)<<4;       // gt read swizzle (64B rows)

    __shared__ __align__(16) char ldsb[32768];
    char* phL = ldsb;               // [2][8192] phi tiles [32 keys][256B], XOR-swizzled
    char* gtL = ldsb + 16384;       // [2][8192] gt tiles [128 o][64B], XOR-swizzled

    // theta B-fragment: lane holds theta[qrow0+cc][d=q*8..]
    f16x8 aq[4];
    const f16* thp = th + ((size_t)(b*NN + qrow0 + cc))*CI + q*8;
    #pragma unroll
    for (int kk=0;kk<4;kk++) aq[kk] = *(const f16x8*)(thp + kk*32);

    const char* phg = (const char*)(ph + (size_t)b*NN*CI);
    const char* gtg = (const char*)gt2 + (size_t)b*64*16384;

    // yacc[os][r] = y^T[o = os*16+4q+r][qrow=cc], unnormalized
    f32x4 yacc[8];
    #pragma unroll
    for (int os=0;os<8;os++) yacc[os]=(f32x4){0,0,0,0};
    float m_run = -1e30f;
    float l_run = 0.f;

    // staging: 32-key tile tt -> buffer bb. LDS dest linear; global source pre-swizzled.
    auto STAGE = [&](int tt, int bb){
        int key0 = kv0 + tt*32;
        int mt  = key0 >> 6;
        int kob = (key0 & 32)*2;       // byte offset of 32-key half within gt2 tile row
        char* pbase = phL + bb*8192 + wv*2048;
        char* gbase = gtL + bb*8192 + wv*2048;
        #pragma unroll
        for (int ch=0; ch<2; ch++){
            int prow = wv*8 + ch*4 + (lane>>4);
            const char* ps = phg + (size_t)(key0 + prow)*256 + (((lane&15)*16) ^ ((prow&7)<<4));
            __builtin_amdgcn_global_load_lds(GL1(ps), LDS3(pbase + ch*1024), 16, 0, 0);
            int gf = wv*2048 + ch*1024 + lane*16;
            int grow = gf>>6, gcol = gf&63;
            const char* gs = gtg + (size_t)mt*16384 + grow*128 + kob + (gcol ^ (((grow>>1)&3)<<4));
            __builtin_amdgcn_global_load_lds(GL1(gs), LDS3(gbase + ch*1024), 16, 0, 0);
        }
    };

    STAGE(0, 0);
    __syncthreads();

    int cur = 0;
    #pragma unroll 1
    for (int it=0; it<32; ++it){
        if (it < 31) STAGE(it+1, cur^1);
        const char* pt  = phL + cur*8192;
        const char* gtt = gtL + cur*8192;
        // swapped QK^T: fa[j][r] = score[key = j*16+4q+r][qrow = cc]
        f32x4 fa[2];
        #pragma unroll
        for (int j=0;j<2;j++){
            f16x8 pf[4];
            #pragma unroll
            for (int kk=0;kk<4;kk++)
                pf[kk] = *(const f16x8*)(pt + (j*16+cc)*256 + ((kk*64 + q*16) ^ sw));
            fa[j]=(f32x4){0,0,0,0};
            #pragma unroll
            for (int kk=0;kk<4;kk++)
                fa[j]=MFMA(pf[kk], aq[kk], fa[j]);   // operands swapped: phi rows -> D rows
        }
        // tile max for this q-row: 7 in-lane fmax + 2 cross-q-group shuffles
        float t0 = fmaxf(fmaxf(fa[0][0],fa[0][1]), fmaxf(fa[0][2],fa[0][3]));
        float t1 = fmaxf(fmaxf(fa[1][0],fa[1][1]), fmaxf(fa[1][2],fa[1][3]));
        float m0 = fmaxf(t0,t1);
        m0 = fmaxf(m0, __shfl_xor(m0,16));
        m0 = fmaxf(m0, __shfl_xor(m0,32));
        // defer-max skip (THR=3)
        if (__any(m0 - m_run > 3.f)){
            float nm = fmaxf(m_run, m0);
            float co = __expf(m_run - nm);
            m_run = nm;
            l_run *= co;
            #pragma unroll
            for (int os=0;os<8;os++) yacc[os] *= co;
        }
        #pragma unroll
        for (int j=0;j<2;j++){
            #pragma unroll
            for (int r=0;r<4;r++) fa[j][r] = __expf(fa[j][r]-m_run);
        }
        l_run += ((fa[0][0]+fa[0][1])+(fa[0][2]+fa[0][3]))
               + ((fa[1][0]+fa[1][1])+(fa[1][2]+fa[1][3]));
        // P stays in registers: B-fragment k-order = key(16*(i>>2) + 4q + (i&3))
        f16x8 pb;
        #pragma unroll
        for (int r=0;r<4;r++){ pb[r]=(f16)fa[0][r]; pb[4+r]=(f16)fa[1][r]; }
        // PV: A = gt rows (o), k in matching key order -> two b64 reads per os
        #pragma unroll
        for (int os=0;os<8;os++){
            int row = os*16 + cc;
            f16x4 lo = *(const f16x4*)(gtt + row*64 + (( 8*q)     ^ sw2));
            f16x4 hi = *(const f16x4*)(gtt + row*64 + ((32 + 8*q) ^ sw2));
            f16x8 ga;
            #pragma unroll
            for (int e=0;e<4;e++){ ga[e]=lo[e]; ga[4+e]=hi[e]; }
            yacc[os] = MFMA(ga, pb, yacc[os]);
        }
        __syncthreads();
        cur ^= 1;
    }
    // final l reduce across q-groups (keys were split across lanes cc, cc+16, cc+32, cc+48)
    float l = l_run;
    l += __shfl_xor(l,16);
    l += __shfl_xor(l,32);
    float linv = 1.f/l;
    // transpose y^T frags through (now-free) staging LDS, then coalesced global write
    f16* yl = (f16*)(ldsb + wv*4096);   // per-wave 16 rows x 128 o x 2B
    #pragma unroll
    for (int os=0;os<8;os++){
        #pragma unroll
        for (int r=0;r<4;r++){
            int o = os*16 + 4*q + r;
            *(f16*)((char*)yl + cc*256 + ((o*2) ^ ((cc&7)<<4))) = (f16)(yacc[os][r]*linv);
        }
    }
    #pragma unroll
    for (int p=0;p<4;p++){
        int idx = p*512 + lane*8;
        int row = idx>>7, o0 = idx&127;
        f16x8 v = *(const f16x8*)((char*)yl + row*256 + ((o0*2) ^ ((row&7)<<4)));
        *(f16x8*)(ypart + ((size_t)((sp*4+b)*NN + qrow0 + row))*CI + o0) = v;
    }
    if (lane < 16){
        size_t row = (size_t)(sp*4+b)*NN + qrow0 + lane;
        ml[row*2]   = m_run;
        ml[row*2+1] = l;
    }
}

// ---------------- K3c: fused combine + Gram/mean stats (MFMA), 64 rows/block, 256 blocks ----------------
__global__ __launch_bounds__(256) void k3c(const f16* ypart, const float* ml,
                                           f16* y, float* part, float* mupart){
    int blk = blockIdx.x; int t = threadIdx.x;     // 256 blocks
    int rloc = t>>2;                   // 0..63
    int row  = blk*64 + rloc;
    int b = row>>12, n = row & 4095;
    int o0 = (t&3)*32;
    __shared__ __align__(16) f16 ldsT[128*64];     // [o][n'] n-swizzled
    float m_s[4], l_s[4];
    #pragma unroll
    for (int s=0;s<4;s++){ size_t r2 = ((size_t)(s*4+b)*NN + n)*2; m_s[s]=ml[r2]; l_s[s]=ml[r2+1]; }
    float M = fmaxf(fmaxf(m_s[0],m_s[1]),fmaxf(m_s[2],m_s[3]));
    float w[4]; float L=0.f;
    #pragma unroll
    for (int s=0;s<4;s++){ w[s]=l_s[s]*__expf(m_s[s]-M); L+=w[s]; }
    float inv = 1.f/L;
    #pragma unroll
    for (int s=0;s<4;s++) w[s]*=inv;
    float acc[32];
    #pragma unroll
    for (int j=0;j<32;j++) acc[j]=0.f;
    #pragma unroll
    for (int s=0;s<4;s++){
        const f16* src = ypart + ((size_t)(s*4+b)*NN + n)*CI + o0;
        #pragma unroll
        for (int v=0;v<4;v++){
            f16x8 vv = *(const f16x8*)(src + v*8);
            #pragma unroll
            for (int e=0;e<8;e++) acc[v*8+e] += w[s]*(float)vv[e];
        }
    }
    f16* yo = y + (size_t)row*CI + o0;
    #pragma unroll
    for (int v=0;v<4;v++){
        f16x8 ov;
        #pragma unroll
        for (int e=0;e<8;e++) ov[e] = (f16)acc[v*8+e];
        *(f16x8*)(yo + v*8) = ov;
        #pragma unroll
        for (int e=0;e<8;e++){
            int o = o0 + v*8 + e;
            ldsT[o*64 + (rloc ^ ((o&7)<<3))] = ov[e];
        }
    }
    __syncthreads();
    // Gram partial via MFMA over 64 rows
    int wv=t>>6, lane=t&63, q=lane>>4, cc=lane&15;
    f32x4 gacc[2][8];
    #pragma unroll
    for (int a=0;a<2;a++)
        #pragma unroll
        for (int c2=0;c2<8;c2++) gacc[a][c2]=(f32x4){0,0,0,0};
    f16x8 af[2][2];
    #pragma unroll
    for (int o1t=0;o1t<2;o1t++){
        int o1 = (wv*2+o1t)*16+cc;
        #pragma unroll
        for (int kk=0;kk<2;kk++)
            af[o1t][kk] = *(const f16x8*)(ldsT + o1*64 + ((kk*32+q*8) ^ ((o1&7)<<3)));
    }
    #pragma unroll 1
    for (int o2t=0;o2t<8;o2t++){
        int o2 = o2t*16+cc;
        #pragma unroll
        for (int kk=0;kk<2;kk++){
            f16x8 bf = *(const f16x8*)(ldsT + o2*64 + ((kk*32+q*8) ^ ((o2&7)<<3)));
            gacc[0][o2t] = MFMA(af[0][kk], bf, gacc[0][o2t]);
            gacc[1][o2t] = MFMA(af[1][kk], bf, gacc[1][o2t]);
        }
    }
    float* pb = part + (size_t)blk*16384;
    #pragma unroll
    for (int o1t=0;o1t<2;o1t++){
        #pragma unroll
        for (int o2t=0;o2t<8;o2t++){
            #pragma unroll
            for (int r=0;r<4;r++)
                pb[((wv*2+o1t)*16+4*q+r)*128 + o2t*16+cc] = gacc[o1t][o2t][r];
        }
    }
    // mean partial
    if (t<128){
        float sm=0.f;
        #pragma unroll
        for (int v=0;v<8;v++){
            f16x8 vv = *(const f16x8*)(ldsT + t*64 + ((v*8) ^ ((t&7)<<3)));
            #pragma unroll
            for (int e=0;e<8;e++) sm += (float)vv[e];
        }
        mupart[blk*128 + t] = sm;
    }
}

// ---------------- K4b: chunked reduce of partials -> atomicAdd into S (pre-zeroed) ----------------
__global__ __launch_bounds__(256) void k4b_red(const float* part, const float* mupart, float* S){
    int pc = blockIdx.y;               // 8 chunks of 32 partials
    int t = threadIdx.x;
    if (blockIdx.x < 64){
        int i = blockIdx.x*256 + t;
        float s=0.f;
        #pragma unroll 1
        for (int p=pc*32; p<pc*32+32; p++) s += part[(size_t)p*16384 + i];
        atomicAdd(&S[i], s);
    } else if (t < 128){
        float s=0.f;
        #pragma unroll 1
        for (int p=pc*32; p<pc*32+32; p++) s += mupart[p*128 + t];
        atomicAdd(&S[16384+t], s);
    }
}

// ---------------- K4c: BN coefficients A[ch], B4[ch] ----------------
__global__ __launch_bounds__(128) void k4c_coef(const float* S, const float* Ww, const float* Wb,
                                                const float* gamma, const float* beta,
                                                const float* scale, float* AB){
    int ch = blockIdx.x; int t = threadIdx.x;
    const float* w = Ww + ch*CI;
    float tmp=0.f;
    const float* Srow = S + t*CI;
    #pragma unroll 1
    for (int o2=0;o2<CI;o2++) tmp += Srow[o2]*w[o2];
    float v  = w[t]*tmp;
    float mc = w[t]*S[16384 + t];
    #pragma unroll
    for (int s=1;s<64;s<<=1){ v += __shfl_xor(v,s); mc += __shfl_xor(mc,s); }
    __shared__ float red[4];
    if ((t&63)==0){ red[(t>>6)*2]=v; red[(t>>6)*2+1]=mc; }
    __syncthreads();
    if (t==0){
        float wSw = red[0]+red[2];
        float wmu = red[1]+red[3];
        const float M = 16384.f;
        float meanwy = wmu/M + Wb[ch];
        float var = wSw/M - (wmu/M)*(wmu/M);
        float inv = rsqrtf(var + 1e-5f);
        float sc = scale[0];
        float A  = sc*gamma[ch]*inv;
        float B3 = sc*(beta[ch] - meanwy*inv*gamma[ch]);
        AB[ch]     = A;
        AB[256+ch] = B3 + A*Wb[ch];
    }
}

// ---------------- K5: fused W-conv + BN + scale + residual, 512 blocks ----------------
__global__ __launch_bounds__(256) void k5_out(const f16* Wwh, const f16* y, const float* x,
                                              const float* AB, float* out){
    int ntile = blockIdx.x;      // 32
    int cht   = blockIdx.y;      // 4
    int b     = blockIdx.z;
    int wv=threadIdx.x>>6, lane=threadIdx.x&63, q=lane>>4, cc=lane&15;
    int ch0 = cht*64 + wv*16;
    f16x8 aw[4];
    const f16* wp = Wwh + ((size_t)(ch0+cc))*CI + q*8;
    #pragma unroll
    for (int kk=0;kk<4;kk++) aw[kk]=*(const f16x8*)(wp+kk*32);
    float Ar[4], Br[4];
    #pragma unroll
    for (int r=0;r<4;r++){ Ar[r]=AB[ch0+4*q+r]; Br[r]=AB[256+ch0+4*q+r]; }
    #pragma unroll 1
    for (int ns=0;ns<8;ns++){
        int n0 = ntile*128 + ns*16;
        f32x4 acc={0,0,0,0};
        const f16* yp = y + ((size_t)(b*NN + n0 + cc))*CI + q*8;
        #pragma unroll
        for (int kk=0;kk<4;kk++) acc = MFMA(aw[kk], *(const f16x8*)(yp+kk*32), acc);
        #pragma unroll
        for (int r=0;r<4;r++){
            size_t addr = ((size_t)(b*CC + ch0 + 4*q + r))*NN + n0 + cc;
            out[addr] = x[addr] + Ar[r]*acc[r] + Br[r];
        }
    }
}

extern "C" void kernel_launch(void* const* d_in, const int* in_sizes, int n_in,
                              void* d_out, int out_size, void* d_ws, size_t ws_size,
                              hipStream_t stream){
    const float* x    = (const float*)d_in[0];
    const float* g_w  = (const float*)d_in[1];
    const float* g_b  = (const float*)d_in[2];
    const float* th_w = (const float*)d_in[3];
    const float* th_b = (const float*)d_in[4];
    const float* ph_w = (const float*)d_in[5];
    const float* ph_b = (const float*)d_in[6];
    const float* W_w  = (const float*)d_in[7];
    const float* W_b  = (const float*)d_in[8];
    const float* bg   = (const float*)d_in[9];
    const float* bb   = (const float*)d_in[10];
    const float* sc   = (const float*)d_in[11];

    char* ws = (char*)d_ws;
    f16* xt  = (f16*)(ws);                                  // 8.4 MB
    f16* th  = (f16*)(ws + 8388608);                        // 4.2 MB
    f16* ph  = (f16*)(ws + 8388608 + 1*4194304);            // 4.2 MB
    f16* gt2 = (f16*)(ws + 8388608 + 2*4194304);            // 4.2 MB (tiled [b][mt][128][64])
    f16* y   = (f16*)(ws + 8388608 + 3*4194304);            // 4.2 MB
    f16* wh  = (f16*)(ws + 8388608 + 4*4194304);            // 256 KB
    float* ml    = (float*)(ws + 25427968);                 // 512 KB
    f16*   ypart = (f16*)(ws + 25952256);                   // 16.8 MB
    float* mupart= (float*)(ws + 42729472);                 // 128 KB
    float* part  = (float*)ws;                              // 16.8 MB overlay on xt+th+ph (dead after k3)
    float* S    = (float*)(ws + 42860544);                  // 66 KB
    float* AB   = (float*)(ws + 42926592);                  // 2 KB
    f16* th_wh = wh;
    f16* ph_wh = wh + 32768;
    f16* g_wh  = wh + 65536;
    f16* Ww_h  = wh + 98304;

    hipMemsetAsync(S, 0, 16512*sizeof(float), stream);
    hipLaunchKernelGGL(k01_xpose, dim3(64,4,4), dim3(256), 0, stream, x, xt, th_w, ph_w, g_w, W_w, wh);
    hipLaunchKernelGGL(k2_all,   dim3(128,4),   dim3(256), 0, stream, xt, th_wh, ph_wh, g_wh,
                       th_b, ph_b, g_b, th, ph, gt2);
    hipLaunchKernelGGL(k3_attn,  dim3(64,4,4),  dim3(256), 0, stream, th, ph, gt2, ypart, ml);
    hipLaunchKernelGGL(k3c,      dim3(256),     dim3(256), 0, stream, ypart, ml, y, part, mupart);
    hipLaunchKernelGGL(k4b_red,  dim3(65,8),    dim3(256), 0, stream, part, mupart, S);
    hipLaunchKernelGGL(k4c_coef, dim3(256),     dim3(128), 0, stream, S, W_w, W_b, bg, bb, sc, AB);
    hipLaunchKernelGGL(k5_out,   dim3(32,4,4),  dim3(256), 0, stream, Ww_h, y, x, AB, (float*)d_out);
}

// Round 11
// 148.620 us; speedup vs baseline: 1.1387x; 1.0490x over previous
//
#include <hip/hip_runtime.h>
#include <hip/hip_bf16.h>

#define BB 4
#define CC 256
#define CI 128
#define NN 4096

typedef _Float16 f16;
typedef __attribute__((ext_vector_type(8))) _Float16 f16x8;
typedef __attribute__((ext_vector_type(4))) _Float16 f16x4;
typedef __attribute__((ext_vector_type(4))) float f32x4;

#define MFMA(a,b,c) __builtin_amdgcn_mfma_f32_16x16x32_f16(a,b,c,0,0,0)
#define LDS3(p) ((__attribute__((address_space(3))) void*)(p))
#define GL1(p)  ((const __attribute__((address_space(1))) void*)(p))

// ---------------- K01: transpose+cast x -> xt, plus weight cast (fused k0) ----------------
__global__ __launch_bounds__(256) void k01_xpose(const float* x, f16* xt,
                                                 const float* tw, const float* pw,
                                                 const float* gw, const float* Ww, f16* wdst){
    int nt = blockIdx.x, ct = blockIdx.y, b = blockIdx.z;
    __shared__ float tile[64][65];
    int t = threadIdx.x;
    const float* src = x + ((size_t)(b*CC + ct*64))*NN + nt*64;
    #pragma unroll
    for (int k=0;k<16;k++){ int idx=t+k*256; int cl=idx>>6, nl=idx&63;
        tile[cl][nl]=src[(size_t)cl*NN + nl]; }
    __syncthreads();
    f16* dst = xt + ((size_t)(b*NN + nt*64))*CC + ct*64;
    #pragma unroll
    for (int k=0;k<16;k++){ int idx=t+k*256; int nl=idx>>6, cl=idx&63;
        dst[(size_t)nl*CC + cl] = (f16)tile[cl][nl]; }
    // fused weight cast: 1024 blocks x 128 elements = 131072
    if (t < 128){
        int blkId = blockIdx.x + 64*(blockIdx.y + 4*blockIdx.z);
        int i = blkId*128 + t;
        int j = i & 32767; int sel = i >> 15;
        const float* s = (sel==0)? tw : (sel==1)? pw : (sel==2)? gw : Ww;
        wdst[i] = (f16)s[j];
    }
}

// ---------------- K2: merged theta/phi/g projections, 512 blocks ----------------
// g output gt2[b][mt][o][64] with keys PERMUTED within each 32-half:
// key K=16j+4a+r stored at p = 8a+4j+r  (so k3's PV A-frag is one b128).
__global__ __launch_bounds__(256) void k2_all(const f16* xt, const f16* thw, const f16* phw,
                                              const f16* gwh, const float* thb, const float* phb,
                                              const float* gb, f16* th, f16* ph, f16* gt2){
    int b = blockIdx.y; int xx = blockIdx.x;
    int wv = threadIdx.x>>6, lane = threadIdx.x&63, q=lane>>4, cc=lane&15;
    if (xx < 64){
        // theta (xx<32) or phi (xx>=32), 128 rows per block
        int mat = xx>>5; int ntile = xx&31;
        int n0 = ntile*128 + wv*32;
        f16x8 aq[2][8];
        #pragma unroll
        for (int ns=0;ns<2;ns++){
            const f16* ap = xt + ((size_t)(b*NN + n0 + ns*16 + cc))*CC + q*8;
            #pragma unroll
            for (int kk=0;kk<8;kk++) aq[ns][kk] = *(const f16x8*)(ap + kk*32);
        }
        const f16* w   = mat? phw : thw;
        const float* bias = mat? phb : thb;
        f16* o = mat? ph : th;
        #pragma unroll 1
        for (int os=0;os<8;os++){
            f32x4 acc0={0,0,0,0}, acc1={0,0,0,0};
            const f16* wp = w + ((size_t)(os*16 + cc))*CC + q*8;
            #pragma unroll
            for (int kk=0;kk<8;kk++){
                f16x8 bf = *(const f16x8*)(wp + kk*32);
                acc0 = MFMA(aq[0][kk], bf, acc0);
                acc1 = MFMA(aq[1][kk], bf, acc1);
            }
            float bv = bias[os*16+cc];
            #pragma unroll
            for (int r=0;r<4;r++){
                o[((size_t)(b*NN + n0      + 4*q + r))*CI + os*16 + cc] = (f16)(acc0[r] + bv);
                o[((size_t)(b*NN + n0 + 16 + 4*q + r))*CI + os*16 + cc] = (f16)(acc1[r] + bv);
            }
        }
    } else {
        // g projection, TILED + key-permuted output
        int mt = xx - 64;
        f16x8 ag[2][8];
        #pragma unroll
        for (int os=0;os<2;os++){
            const f16* ap = gwh + ((size_t)(wv*32 + os*16 + cc))*CC + q*8;
            #pragma unroll
            for (int kk=0;kk<8;kk++) ag[os][kk] = *(const f16x8*)(ap + kk*32);
        }
        f32x4 acc[2][4];
        #pragma unroll
        for (int os=0;os<2;os++){
            #pragma unroll
            for (int ms=0;ms<4;ms++) acc[os][ms]=(f32x4){0,0,0,0};
        }
        #pragma unroll 1
        for (int kk=0;kk<8;kk++){
            #pragma unroll
            for (int ms=0;ms<4;ms++){
                f16x8 bf = *(const f16x8*)(xt + ((size_t)(b*NN + mt*64 + ms*16 + cc))*CC + kk*32 + q*8);
                acc[0][ms]=MFMA(ag[0][kk],bf,acc[0][ms]);
                acc[1][ms]=MFMA(ag[1][kk],bf,acc[1][ms]);
            }
        }
        // key within tile = ms*16+cc -> half h=ms>>1, permuted pos = 8*(cc>>2)+4*(ms&1)+(cc&3)
        #pragma unroll
        for (int os=0;os<2;os++){
            #pragma unroll
            for (int r=0;r<4;r++){
                int orow = wv*32 + os*16 + 4*q + r;
                float bv = gb[orow];
                #pragma unroll
                for (int ms=0;ms<4;ms++){
                    int pos = (ms>>1)*32 + 8*(cc>>2) + 4*(ms&1) + (cc&3);
                    gt2[((size_t)(b*64 + mt))*8192 + orow*64 + pos] = (f16)(acc[os][ms][r] + bv);
                }
            }
        }
    }
}

// ---------------- K3: flash attention, swapped QK^T (P in registers), b128 PV, 32KB LDS ----------------
__global__ __launch_bounds__(256, 4) void k3_attn(const f16* th, const f16* ph, const f16* gt2,
                                                  f16* ypart, float* ml){
    int qt = blockIdx.x;           // 64 q-tiles of 64 rows
    int sp = blockIdx.y;           // 4 key splits of 1024 keys
    int b  = blockIdx.z;           // 4 batches
    int wv=threadIdx.x>>6, lane=threadIdx.x&63, q=lane>>4, cc=lane&15;
    int qrow0 = qt*64 + wv*16;
    int kv0 = sp*1024;
    int sw  = (cc&7)<<4;            // phi read swizzle (256B rows)
    int sw2 = ((cc>>1)&3)<<4;       // gt read swizzle (64B rows)

    __shared__ __align__(16) char ldsb[32768];
    char* phL = ldsb;               // [2][8192] phi tiles [32 keys][256B], XOR-swizzled
    char* gtL = ldsb + 16384;       // [2][8192] gt tiles [128 o][64B], XOR-swizzled, key-permuted

    // theta B-fragment: lane holds theta[qrow0+cc][d=q*8..]
    f16x8 aq[4];
    const f16* thp = th + ((size_t)(b*NN + qrow0 + cc))*CI + q*8;
    #pragma unroll
    for (int kk=0;kk<4;kk++) aq[kk] = *(const f16x8*)(thp + kk*32);

    const char* phg = (const char*)(ph + (size_t)b*NN*CI);
    const char* gtg = (const char*)gt2 + (size_t)b*64*16384;

    // yacc[os][r] = y^T[o = os*16+4q+r][qrow=cc], unnormalized
    f32x4 yacc[8];
    #pragma unroll
    for (int os=0;os<8;os++) yacc[os]=(f32x4){0,0,0,0};
    float m_run = -1e30f;
    float l_run = 0.f;

    // staging: 32-key tile tt -> buffer bb. LDS dest linear; global source pre-swizzled.
    auto STAGE = [&](int tt, int bb){
        int key0 = kv0 + tt*32;
        int mt  = key0 >> 6;
        int kob = (key0 & 32)*2;       // byte offset of 32-key half within gt2 tile row
        char* pbase = phL + bb*8192 + wv*2048;
        char* gbase = gtL + bb*8192 + wv*2048;
        #pragma unroll
        for (int ch=0; ch<2; ch++){
            int prow = wv*8 + ch*4 + (lane>>4);
            const char* ps = phg + (size_t)(key0 + prow)*256 + (((lane&15)*16) ^ ((prow&7)<<4));
            __builtin_amdgcn_global_load_lds(GL1(ps), LDS3(pbase + ch*1024), 16, 0, 0);
            int gf = wv*2048 + ch*1024 + lane*16;
            int grow = gf>>6, gcol = gf&63;
            const char* gs = gtg + (size_t)mt*16384 + grow*128 + kob + (gcol ^ (((grow>>1)&3)<<4));
            __builtin_amdgcn_global_load_lds(GL1(gs), LDS3(gbase + ch*1024), 16, 0, 0);
        }
    };

    STAGE(0, 0);
    __syncthreads();

    int cur = 0;
    #pragma unroll 1
    for (int it=0; it<32; ++it){
        if (it < 31) STAGE(it+1, cur^1);
        const char* pt  = phL + cur*8192;
        const char* gtt = gtL + cur*8192;
        // swapped QK^T: fa[j][r] = score[key = j*16+4q+r][qrow = cc]
        f32x4 fa[2];
        #pragma unroll
        for (int j=0;j<2;j++){
            f16x8 pf[4];
            #pragma unroll
            for (int kk=0;kk<4;kk++)
                pf[kk] = *(const f16x8*)(pt + (j*16+cc)*256 + ((kk*64 + q*16) ^ sw));
            fa[j]=(f32x4){0,0,0,0};
            #pragma unroll
            for (int kk=0;kk<4;kk++)
                fa[j]=MFMA(pf[kk], aq[kk], fa[j]);   // operands swapped: phi rows -> D rows
        }
        // tile max for this q-row: 7 in-lane fmax + 2 cross-q-group shuffles
        float t0 = fmaxf(fmaxf(fa[0][0],fa[0][1]), fmaxf(fa[0][2],fa[0][3]));
        float t1 = fmaxf(fmaxf(fa[1][0],fa[1][1]), fmaxf(fa[1][2],fa[1][3]));
        float m0 = fmaxf(t0,t1);
        m0 = fmaxf(m0, __shfl_xor(m0,16));
        m0 = fmaxf(m0, __shfl_xor(m0,32));
        // defer-max skip (THR=3)
        if (__any(m0 - m_run > 3.f)){
            float nm = fmaxf(m_run, m0);
            float co = __expf(m_run - nm);
            m_run = nm;
            l_run *= co;
            #pragma unroll
            for (int os=0;os<8;os++) yacc[os] *= co;
        }
        #pragma unroll
        for (int j=0;j<2;j++){
            #pragma unroll
            for (int r=0;r<4;r++) fa[j][r] = __expf(fa[j][r]-m_run);
        }
        l_run += ((fa[0][0]+fa[0][1])+(fa[0][2]+fa[0][3]))
               + ((fa[1][0]+fa[1][1])+(fa[1][2]+fa[1][3]));
        // P stays in registers: logical-k order = key(16*(e>>2) + 4q + (e&3))
        f16x8 pb;
        #pragma unroll
        for (int r=0;r<4;r++){ pb[r]=(f16)fa[0][r]; pb[4+r]=(f16)fa[1][r]; }
        // PV: A = gt rows (o); gt2 key-permutation makes the fragment one b128 read
        #pragma unroll
        for (int os=0;os<8;os++){
            int row = os*16 + cc;
            f16x8 ga = *(const f16x8*)(gtt + row*64 + ((q*16) ^ sw2));
            yacc[os] = MFMA(ga, pb, yacc[os]);
        }
        __syncthreads();
        cur ^= 1;
    }
    // final l reduce across q-groups (keys were split across lanes cc, cc+16, cc+32, cc+48)
    float l = l_run;
    l += __shfl_xor(l,16);
    l += __shfl_xor(l,32);
    float linv = 1.f/l;
    // transpose y^T frags through (now-free) staging LDS, then coalesced global write
    f16* yl = (f16*)(ldsb + wv*4096);   // per-wave 16 rows x 128 o x 2B
    #pragma unroll
    for (int os=0;os<8;os++){
        #pragma unroll
        for (int r=0;r<4;r++){
            int o = os*16 + 4*q + r;
            *(f16*)((char*)yl + cc*256 + ((o*2) ^ ((cc&7)<<4))) = (f16)(yacc[os][r]*linv);
        }
    }
    #pragma unroll
    for (int p=0;p<4;p++){
        int idx = p*512 + lane*8;
        int row = idx>>7, o0 = idx&127;
        f16x8 v = *(const f16x8*)((char*)yl + row*256 + ((o0*2) ^ ((row&7)<<4)));
        *(f16x8*)(ypart + ((size_t)((sp*4+b)*NN + qrow0 + row))*CI + o0) = v;
    }
    if (lane < 16){
        size_t row = (size_t)(sp*4+b)*NN + qrow0 + lane;
        ml[row*2]   = m_run;
        ml[row*2+1] = l;
    }
}

// ---------------- K3c: fused combine + Gram/mean stats (MFMA), 64 rows/block, 256 blocks ----------------
__global__ __launch_bounds__(256) void k3c(const f16* ypart, const float* ml,
                                           f16* y, float* part, float* mupart){
    int blk = blockIdx.x; int t = threadIdx.x;     // 256 blocks
    int rloc = t>>2;                   // 0..63
    int row  = blk*64 + rloc;
    int b = row>>12, n = row & 4095;
    int o0 = (t&3)*32;
    __shared__ __align__(16) f16 ldsT[128*64];     // [o][n'] n-swizzled
    float m_s[4], l_s[4];
    #pragma unroll
    for (int s=0;s<4;s++){ size_t r2 = ((size_t)(s*4+b)*NN + n)*2; m_s[s]=ml[r2]; l_s[s]=ml[r2+1]; }
    float M = fmaxf(fmaxf(m_s[0],m_s[1]),fmaxf(m_s[2],m_s[3]));
    float w[4]; float L=0.f;
    #pragma unroll
    for (int s=0;s<4;s++){ w[s]=l_s[s]*__expf(m_s[s]-M); L+=w[s]; }
    float inv = 1.f/L;
    #pragma unroll
    for (int s=0;s<4;s++) w[s]*=inv;
    float acc[32];
    #pragma unroll
    for (int j=0;j<32;j++) acc[j]=0.f;
    #pragma unroll
    for (int s=0;s<4;s++){
        const f16* src = ypart + ((size_t)(s*4+b)*NN + n)*CI + o0;
        #pragma unroll
        for (int v=0;v<4;v++){
            f16x8 vv = *(const f16x8*)(src + v*8);
            #pragma unroll
            for (int e=0;e<8;e++) acc[v*8+e] += w[s]*(float)vv[e];
        }
    }
    f16* yo = y + (size_t)row*CI + o0;
    #pragma unroll
    for (int v=0;v<4;v++){
        f16x8 ov;
        #pragma unroll
        for (int e=0;e<8;e++) ov[e] = (f16)acc[v*8+e];
        *(f16x8*)(yo + v*8) = ov;
        #pragma unroll
        for (int e=0;e<8;e++){
            int o = o0 + v*8 + e;
            ldsT[o*64 + (rloc ^ ((o&7)<<3))] = ov[e];
        }
    }
    __syncthreads();
    // Gram partial via MFMA over 64 rows
    int wv=t>>6, lane=t&63, q=lane>>4, cc=lane&15;
    f32x4 gacc[2][8];
    #pragma unroll
    for (int a=0;a<2;a++)
        #pragma unroll
        for (int c2=0;c2<8;c2++) gacc[a][c2]=(f32x4){0,0,0,0};
    f16x8 af[2][2];
    #pragma unroll
    for (int o1t=0;o1t<2;o1t++){
        int o1 = (wv*2+o1t)*16+cc;
        #pragma unroll
        for (int kk=0;kk<2;kk++)
            af[o1t][kk] = *(const f16x8*)(ldsT + o1*64 + ((kk*32+q*8) ^ ((o1&7)<<3)));
    }
    #pragma unroll 1
    for (int o2t=0;o2t<8;o2t++){
        int o2 = o2t*16+cc;
        #pragma unroll
        for (int kk=0;kk<2;kk++){
            f16x8 bf = *(const f16x8*)(ldsT + o2*64 + ((kk*32+q*8) ^ ((o2&7)<<3)));
            gacc[0][o2t] = MFMA(af[0][kk], bf, gacc[0][o2t]);
            gacc[1][o2t] = MFMA(af[1][kk], bf, gacc[1][o2t]);
        }
    }
    float* pb = part + (size_t)blk*16384;
    #pragma unroll
    for (int o1t=0;o1t<2;o1t++){
        #pragma unroll
        for (int o2t=0;o2t<8;o2t++){
            #pragma unroll
            for (int r=0;r<4;r++)
                pb[((wv*2+o1t)*16+4*q+r)*128 + o2t*16+cc] = gacc[o1t][o2t][r];
        }
    }
    // mean partial
    if (t<128){
        float sm=0.f;
        #pragma unroll
        for (int v=0;v<8;v++){
            f16x8 vv = *(const f16x8*)(ldsT + t*64 + ((v*8) ^ ((t&7)<<3)));
            #pragma unroll
            for (int e=0;e<8;e++) sm += (float)vv[e];
        }
        mupart[blk*128 + t] = sm;
    }
}

// ---------------- K4b: chunked reduce of partials -> atomicAdd into S (pre-zeroed) ----------------
__global__ __launch_bounds__(256) void k4b_red(const float* part, const float* mupart, float* S){
    int pc = blockIdx.y;               // 8 chunks of 32 partials
    int t = threadIdx.x;
    if (blockIdx.x < 64){
        int i = blockIdx.x*256 + t;
        float s=0.f;
        #pragma unroll 1
        for (int p=pc*32; p<pc*32+32; p++) s += part[(size_t)p*16384 + i];
        atomicAdd(&S[i], s);
    } else if (t < 128){
        float s=0.f;
        #pragma unroll 1
        for (int p=pc*32; p<pc*32+32; p++) s += mupart[p*128 + t];
        atomicAdd(&S[16384+t], s);
    }
}

// ---------------- K4c: BN coefficients A[ch], B4[ch] ----------------
__global__ __launch_bounds__(128) void k4c_coef(const float* S, const float* Ww, const float* Wb,
                                                const float* gamma, const float* beta,
                                                const float* scale, float* AB){
    int ch = blockIdx.x; int t = threadIdx.x;
    const float* w = Ww + ch*CI;
    float tmp=0.f;
    const float* Srow = S + t*CI;
    #pragma unroll 1
    for (int o2=0;o2<CI;o2++) tmp += Srow[o2]*w[o2];
    float v  = w[t]*tmp;
    float mc = w[t]*S[16384 + t];
    #pragma unroll
    for (int s=1;s<64;s<<=1){ v += __shfl_xor(v,s); mc += __shfl_xor(mc,s); }
    __shared__ float red[4];
    if ((t&63)==0){ red[(t>>6)*2]=v; red[(t>>6)*2+1]=mc; }
    __syncthreads();
    if (t==0){
        float wSw = red[0]+red[2];
        float wmu = red[1]+red[3];
        const float M = 16384.f;
        float meanwy = wmu/M + Wb[ch];
        float var = wSw/M - (wmu/M)*(wmu/M);
        float inv = rsqrtf(var + 1e-5f);
        float sc = scale[0];
        float A  = sc*gamma[ch]*inv;
        float B3 = sc*(beta[ch] - meanwy*inv*gamma[ch]);
        AB[ch]     = A;
        AB[256+ch] = B3 + A*Wb[ch];
    }
}

// ---------------- K5: fused W-conv + BN + scale + residual, 512 blocks ----------------
__global__ __launch_bounds__(256) void k5_out(const f16* Wwh, const f16* y, const float* x,
                                              const float* AB, float* out){
    int ntile = blockIdx.x;      // 32
    int cht   = blockIdx.y;      // 4
    int b     = blockIdx.z;
    int wv=threadIdx.x>>6, lane=threadIdx.x&63, q=lane>>4, cc=lane&15;
    int ch0 = cht*64 + wv*16;
    f16x8 aw[4];
    const f16* wp = Wwh + ((size_t)(ch0+cc))*CI + q*8;
    #pragma unroll
    for (int kk=0;kk<4;kk++) aw[kk]=*(const f16x8*)(wp+kk*32);
    float Ar[4], Br[4];
    #pragma unroll
    for (int r=0;r<4;r++){ Ar[r]=AB[ch0+4*q+r]; Br[r]=AB[256+ch0+4*q+r]; }
    #pragma unroll 1
    for (int ns=0;ns<8;ns++){
        int n0 = ntile*128 + ns*16;
        f32x4 acc={0,0,0,0};
        const f16* yp = y + ((size_t)(b*NN + n0 + cc))*CI + q*8;
        #pragma unroll
        for (int kk=0;kk<4;kk++) acc = MFMA(aw[kk], *(const f16x8*)(yp+kk*32), acc);
        #pragma unroll
        for (int r=0;r<4;r++){
            size_t addr = ((size_t)(b*CC + ch0 + 4*q + r))*NN + n0 + cc;
            out[addr] = x[addr] + Ar[r]*acc[r] + Br[r];
        }
    }
}

extern "C" void kernel_launch(void* const* d_in, const int* in_sizes, int n_in,
                              void* d_out, int out_size, void* d_ws, size_t ws_size,
                              hipStream_t stream){
    const float* x    = (const float*)d_in[0];
    const float* g_w  = (const float*)d_in[1];
    const float* g_b  = (const float*)d_in[2];
    const float* th_w = (const float*)d_in[3];
    const float* th_b = (const float*)d_in[4];
    const float* ph_w = (const float*)d_in[5];
    const float* ph_b = (const float*)d_in[6];
    const float* W_w  = (const float*)d_in[7];
    const float* W_b  = (const float*)d_in[8];
    const float* bg   = (const float*)d_in[9];
    const float* bb   = (const float*)d_in[10];
    const float* sc   = (const float*)d_in[11];

    char* ws = (char*)d_ws;
    f16* xt  = (f16*)(ws);                                  // 8.4 MB
    f16* th  = (f16*)(ws + 8388608);                        // 4.2 MB
    f16* ph  = (f16*)(ws + 8388608 + 1*4194304);            // 4.2 MB
    f16* gt2 = (f16*)(ws + 8388608 + 2*4194304);            // 4.2 MB (tiled [b][mt][128][64], key-permuted)
    f16* y   = (f16*)(ws + 8388608 + 3*4194304);            // 4.2 MB
    f16* wh  = (f16*)(ws + 8388608 + 4*4194304);            // 256 KB
    float* ml    = (float*)(ws + 25427968);                 // 512 KB
    f16*   ypart = (f16*)(ws + 25952256);                   // 16.8 MB
    float* mupart= (float*)(ws + 42729472);                 // 128 KB
    float* part  = (float*)ws;                              // 16.8 MB overlay on xt+th+ph (dead after k3)
    float* S    = (float*)(ws + 42860544);                  // 66 KB
    float* AB   = (float*)(ws + 42926592);                  // 2 KB
    f16* th_wh = wh;
    f16* ph_wh = wh + 32768;
    f16* g_wh  = wh + 65536;
    f16* Ww_h  = wh + 98304;

    hipMemsetAsync(S, 0, 16512*sizeof(float), stream);
    hipLaunchKernelGGL(k01_xpose, dim3(64,4,4), dim3(256), 0, stream, x, xt, th_w, ph_w, g_w, W_w, wh);
    hipLaunchKernelGGL(k2_all,   dim3(128,4),   dim3(256), 0, stream, xt, th_wh, ph_wh, g_wh,
                       th_b, ph_b, g_b, th, ph, gt2);
    hipLaunchKernelGGL(k3_attn,  dim3(64,4,4),  dim3(256), 0, stream, th, ph, gt2, ypart, ml);
    hipLaunchKernelGGL(k3c,      dim3(256),     dim3(256), 0, stream, ypart, ml, y, part, mupart);
    hipLaunchKernelGGL(k4b_red,  dim3(65,8),    dim3(256), 0, stream, part, mupart, S);
    hipLaunchKernelGGL(k4c_coef, dim3(256),     dim3(128), 0, stream, S, W_w, W_b, bg, bb, sc, AB);
    hipLaunchKernelGGL(k5_out,   dim3(32,4,4),  dim3(256), 0, stream, Ww_h, y, x, AB, (float*)d_out);
}

// Round 12
// 139.147 us; speedup vs baseline: 1.2162x; 1.0681x over previous
//
#include <hip/hip_runtime.h>
#include <hip/hip_bf16.h>

#define BB 4
#define CC 256
#define CI 128
#define NN 4096

typedef _Float16 f16;
typedef __attribute__((ext_vector_type(8))) _Float16 f16x8;
typedef __attribute__((ext_vector_type(4))) _Float16 f16x4;
typedef __attribute__((ext_vector_type(4))) float f32x4;

#define MFMA(a,b,c) __builtin_amdgcn_mfma_f32_16x16x32_f16(a,b,c,0,0,0)
#define LDS3(p) ((__attribute__((address_space(3))) void*)(p))
#define GL1(p)  ((const __attribute__((address_space(1))) void*)(p))

// ---------------- K01: transpose+cast x -> xt, plus weight cast (fused k0) ----------------
__global__ __launch_bounds__(256) void k01_xpose(const float* x, f16* xt,
                                                 const float* tw, const float* pw,
                                                 const float* gw, const float* Ww, f16* wdst){
    int nt = blockIdx.x, ct = blockIdx.y, b = blockIdx.z;
    __shared__ float tile[64][65];
    int t = threadIdx.x;
    const float* src = x + ((size_t)(b*CC + ct*64))*NN + nt*64;
    #pragma unroll
    for (int k=0;k<16;k++){ int idx=t+k*256; int cl=idx>>6, nl=idx&63;
        tile[cl][nl]=src[(size_t)cl*NN + nl]; }
    __syncthreads();
    f16* dst = xt + ((size_t)(b*NN + nt*64))*CC + ct*64;
    #pragma unroll
    for (int k=0;k<16;k++){ int idx=t+k*256; int nl=idx>>6, cl=idx&63;
        dst[(size_t)nl*CC + cl] = (f16)tile[cl][nl]; }
    // fused weight cast: 1024 blocks x 128 elements = 131072
    if (t < 128){
        int blkId = blockIdx.x + 64*(blockIdx.y + 4*blockIdx.z);
        int i = blkId*128 + t;
        int j = i & 32767; int sel = i >> 15;
        const float* s = (sel==0)? tw : (sel==1)? pw : (sel==2)? gw : Ww;
        wdst[i] = (f16)s[j];
    }
}

// ---------------- K2: merged theta/phi/g projections, 512 blocks ----------------
// g output gt2[b][mt][o][64] with keys PERMUTED within each 32-half:
// key K=16j+4a+r stored at p = 8a+4j+r  (so k3's PV A-frag is one b128).
__global__ __launch_bounds__(256) void k2_all(const f16* xt, const f16* thw, const f16* phw,
                                              const f16* gwh, const float* thb, const float* phb,
                                              const float* gb, f16* th, f16* ph, f16* gt2){
    int b = blockIdx.y; int xx = blockIdx.x;
    int wv = threadIdx.x>>6, lane = threadIdx.x&63, q=lane>>4, cc=lane&15;
    if (xx < 64){
        // theta (xx<32) or phi (xx>=32), 128 rows per block
        int mat = xx>>5; int ntile = xx&31;
        int n0 = ntile*128 + wv*32;
        f16x8 aq[2][8];
        #pragma unroll
        for (int ns=0;ns<2;ns++){
            const f16* ap = xt + ((size_t)(b*NN + n0 + ns*16 + cc))*CC + q*8;
            #pragma unroll
            for (int kk=0;kk<8;kk++) aq[ns][kk] = *(const f16x8*)(ap + kk*32);
        }
        const f16* w   = mat? phw : thw;
        const float* bias = mat? phb : thb;
        f16* o = mat? ph : th;
        #pragma unroll 1
        for (int os=0;os<8;os++){
            f32x4 acc0={0,0,0,0}, acc1={0,0,0,0};
            const f16* wp = w + ((size_t)(os*16 + cc))*CC + q*8;
            #pragma unroll
            for (int kk=0;kk<8;kk++){
                f16x8 bf = *(const f16x8*)(wp + kk*32);
                acc0 = MFMA(aq[0][kk], bf, acc0);
                acc1 = MFMA(aq[1][kk], bf, acc1);
            }
            float bv = bias[os*16+cc];
            #pragma unroll
            for (int r=0;r<4;r++){
                o[((size_t)(b*NN + n0      + 4*q + r))*CI + os*16 + cc] = (f16)(acc0[r] + bv);
                o[((size_t)(b*NN + n0 + 16 + 4*q + r))*CI + os*16 + cc] = (f16)(acc1[r] + bv);
            }
        }
    } else {
        // g projection, TILED + key-permuted output
        int mt = xx - 64;
        f16x8 ag[2][8];
        #pragma unroll
        for (int os=0;os<2;os++){
            const f16* ap = gwh + ((size_t)(wv*32 + os*16 + cc))*CC + q*8;
            #pragma unroll
            for (int kk=0;kk<8;kk++) ag[os][kk] = *(const f16x8*)(ap + kk*32);
        }
        f32x4 acc[2][4];
        #pragma unroll
        for (int os=0;os<2;os++){
            #pragma unroll
            for (int ms=0;ms<4;ms++) acc[os][ms]=(f32x4){0,0,0,0};
        }
        #pragma unroll 1
        for (int kk=0;kk<8;kk++){
            #pragma unroll
            for (int ms=0;ms<4;ms++){
                f16x8 bf = *(const f16x8*)(xt + ((size_t)(b*NN + mt*64 + ms*16 + cc))*CC + kk*32 + q*8);
                acc[0][ms]=MFMA(ag[0][kk],bf,acc[0][ms]);
                acc[1][ms]=MFMA(ag[1][kk],bf,acc[1][ms]);
            }
        }
        // key within tile = ms*16+cc -> half h=ms>>1, permuted pos = 8*(cc>>2)+4*(ms&1)+(cc&3)
        #pragma unroll
        for (int os=0;os<2;os++){
            #pragma unroll
            for (int r=0;r<4;r++){
                int orow = wv*32 + os*16 + 4*q + r;
                float bv = gb[orow];
                #pragma unroll
                for (int ms=0;ms<4;ms++){
                    int pos = (ms>>1)*32 + 8*(cc>>2) + 4*(ms&1) + (cc&3);
                    gt2[((size_t)(b*64 + mt))*8192 + orow*64 + pos] = (f16)(acc[os][ms][r] + bv);
                }
            }
        }
    }
}

// ---------------- K3: flash attention, 32 q-rows/wave, KVBLK=64, swapped-P, 64KB LDS ----------------
__global__ __launch_bounds__(256, 2) void k3_attn(const f16* th, const f16* ph, const f16* gt2,
                                                  f16* ypart, float* ml){
    int qt = blockIdx.x;           // 32 q-tiles of 128 rows (4 waves x 32)
    int sp = blockIdx.y;           // 4 key splits of 1024 keys
    int b  = blockIdx.z;           // 4 batches
    int wv=threadIdx.x>>6, lane=threadIdx.x&63, q=lane>>4, cc=lane&15;
    int qrow0 = qt*128 + wv*32;
    int kv0 = sp*1024;
    int sw  = cc<<4;                        // phi read swizzle (2-way exact)
    int hb  = (cc>>2)&1;                    // gt half-swap bit
    int c6  = (q*16) ^ (((cc>>3)&1)<<4);    // gt within-half offset

    __shared__ __align__(16) char ldsb[65536];
    char* phL = ldsb;                 // [2][16384] phi [64 keys][256B], XOR-swizzled
    char* gtL = ldsb + 32768;         // [2][16384] gt [128 o][128B], half-swapped + swizzled

    // theta B-fragments: lane holds theta[qrow0 + rb*16 + cc][d=q*8..]
    f16x8 aq[2][4];
    #pragma unroll
    for (int rb=0;rb<2;rb++){
        const f16* thp = th + ((size_t)(b*NN + qrow0 + rb*16 + cc))*CI + q*8;
        #pragma unroll
        for (int kk=0;kk<4;kk++) aq[rb][kk] = *(const f16x8*)(thp + kk*32);
    }

    const char* phg = (const char*)(ph + (size_t)b*NN*CI);
    const char* gtg = (const char*)gt2 + (size_t)b*64*16384;

    f32x4 yacc[2][8];
    #pragma unroll
    for (int rb=0;rb<2;rb++)
        #pragma unroll
        for (int os=0;os<8;os++) yacc[rb][os]=(f32x4){0,0,0,0};
    float m_run0=-1e30f, m_run1=-1e30f, l_run0=0.f, l_run1=0.f;

    // staging: 64-key tile tt -> buffer bb. LDS dest linear; global source pre-swizzled.
    auto STAGE = [&](int tt, int bb){
        int key0 = kv0 + tt*64;
        int mt  = key0 >> 6;
        char* pbase = phL + bb*16384 + wv*4096;
        char* gbase = gtL + bb*16384 + wv*4096;
        #pragma unroll
        for (int ch=0; ch<4; ch++){
            int prow = wv*16 + ch*4 + (lane>>4);
            const char* ps = phg + (size_t)(key0 + prow)*256 + (((lane&15)*16) ^ ((prow&15)<<4));
            __builtin_amdgcn_global_load_lds(GL1(ps), LDS3(pbase + ch*1024), 16, 0, 0);
            int gf = wv*4096 + ch*1024 + lane*16;
            int grow = gf>>7, gcol = gf&127;
            int scol = (((gcol>>6) ^ ((grow>>2)&1))<<6) | ((gcol&63) ^ (((grow>>3)&1)<<4));
            const char* gs = gtg + (size_t)mt*16384 + grow*128 + scol;
            __builtin_amdgcn_global_load_lds(GL1(gs), LDS3(gbase + ch*1024), 16, 0, 0);
        }
    };

    STAGE(0, 0);
    __syncthreads();

    int cur = 0;
    #pragma unroll 1
    for (int it=0; it<16; ++it){
        if (it < 15) STAGE(it+1, cur^1);
        const char* pt  = phL + cur*16384;
        const char* gtt = gtL + cur*16384;
        // swapped QK^T: fa[rb][j][r] = score[key = 16j+4q+r][qrow = rb*16+cc]
        f32x4 fa[2][4];
        #pragma unroll
        for (int j=0;j<4;j++){
            f16x8 pf[4];
            #pragma unroll
            for (int kk=0;kk<4;kk++)
                pf[kk] = *(const f16x8*)(pt + (j*16+cc)*256 + ((kk*64 + q*16) ^ sw));
            fa[0][j]=(f32x4){0,0,0,0}; fa[1][j]=(f32x4){0,0,0,0};
            #pragma unroll
            for (int kk=0;kk<4;kk++){
                fa[0][j]=MFMA(pf[kk], aq[0][kk], fa[0][j]);
                fa[1][j]=MFMA(pf[kk], aq[1][kk], fa[1][j]);
            }
        }
        // per-row tile max: 15 in-lane fmax + 2 cross-q-group shuffles, per rb
        float mA0 = fmaxf(fmaxf(fa[0][0][0],fa[0][0][1]),fmaxf(fa[0][0][2],fa[0][0][3]));
        float mA1 = fmaxf(fmaxf(fa[0][1][0],fa[0][1][1]),fmaxf(fa[0][1][2],fa[0][1][3]));
        float mA2 = fmaxf(fmaxf(fa[0][2][0],fa[0][2][1]),fmaxf(fa[0][2][2],fa[0][2][3]));
        float mA3 = fmaxf(fmaxf(fa[0][3][0],fa[0][3][1]),fmaxf(fa[0][3][2],fa[0][3][3]));
        float mx0 = fmaxf(fmaxf(mA0,mA1),fmaxf(mA2,mA3));
        mx0 = fmaxf(mx0, __shfl_xor(mx0,16));
        mx0 = fmaxf(mx0, __shfl_xor(mx0,32));
        float mB0 = fmaxf(fmaxf(fa[1][0][0],fa[1][0][1]),fmaxf(fa[1][0][2],fa[1][0][3]));
        float mB1 = fmaxf(fmaxf(fa[1][1][0],fa[1][1][1]),fmaxf(fa[1][1][2],fa[1][1][3]));
        float mB2 = fmaxf(fmaxf(fa[1][2][0],fa[1][2][1]),fmaxf(fa[1][2][2],fa[1][2][3]));
        float mB3 = fmaxf(fmaxf(fa[1][3][0],fa[1][3][1]),fmaxf(fa[1][3][2],fa[1][3][3]));
        float mx1 = fmaxf(fmaxf(mB0,mB1),fmaxf(mB2,mB3));
        mx1 = fmaxf(mx1, __shfl_xor(mx1,16));
        mx1 = fmaxf(mx1, __shfl_xor(mx1,32));
        // defer-max skip (THR=3)
        float need = fmaxf(mx0 - m_run0, mx1 - m_run1);
        if (__any(need > 3.f)){
            float nm0 = fmaxf(m_run0, mx0), nm1 = fmaxf(m_run1, mx1);
            float co0 = __expf(m_run0 - nm0), co1 = __expf(m_run1 - nm1);
            m_run0 = nm0; m_run1 = nm1;
            l_run0 *= co0; l_run1 *= co1;
            #pragma unroll
            for (int os=0;os<8;os++){ yacc[0][os] *= co0; yacc[1][os] *= co1; }
        }
        #pragma unroll
        for (int j=0;j<4;j++){
            #pragma unroll
            for (int r=0;r<4;r++){
                fa[0][j][r] = __expf(fa[0][j][r]-m_run0);
                fa[1][j][r] = __expf(fa[1][j][r]-m_run1);
            }
        }
        l_run0 += ((fa[0][0][0]+fa[0][0][1]+fa[0][0][2]+fa[0][0][3])
                 + (fa[0][1][0]+fa[0][1][1]+fa[0][1][2]+fa[0][1][3]))
                + ((fa[0][2][0]+fa[0][2][1]+fa[0][2][2]+fa[0][2][3])
                 + (fa[0][3][0]+fa[0][3][1]+fa[0][3][2]+fa[0][3][3]));
        l_run1 += ((fa[1][0][0]+fa[1][0][1]+fa[1][0][2]+fa[1][0][3])
                 + (fa[1][1][0]+fa[1][1][1]+fa[1][1][2]+fa[1][1][3]))
                + ((fa[1][2][0]+fa[1][2][1]+fa[1][2][2]+fa[1][2][3])
                 + (fa[1][3][0]+fa[1][3][1]+fa[1][3][2]+fa[1][3][3]));
        // P in registers: half h frag element i=4j'+r -> fa[rb][2h+j'][r]
        f16x8 pb0h0, pb0h1, pb1h0, pb1h1;
        #pragma unroll
        for (int r=0;r<4;r++){
            pb0h0[r]=(f16)fa[0][0][r]; pb0h0[4+r]=(f16)fa[0][1][r];
            pb0h1[r]=(f16)fa[0][2][r]; pb0h1[4+r]=(f16)fa[0][3][r];
            pb1h0[r]=(f16)fa[1][0][r]; pb1h0[4+r]=(f16)fa[1][1][r];
            pb1h1[r]=(f16)fa[1][2][r]; pb1h1[4+r]=(f16)fa[1][3][r];
        }
        // PV: ga[h] read once per os, reused for both row-blocks
        #pragma unroll
        for (int os=0;os<8;os++){
            int row = os*16 + cc;
            f16x8 ga0 = *(const f16x8*)(gtt + row*128 + ((hb    )<<6) + c6);
            f16x8 ga1 = *(const f16x8*)(gtt + row*128 + ((1 ^ hb)<<6) + c6);
            yacc[0][os] = MFMA(ga0, pb0h0, yacc[0][os]);
            yacc[1][os] = MFMA(ga0, pb1h0, yacc[1][os]);
            yacc[0][os] = MFMA(ga1, pb0h1, yacc[0][os]);
            yacc[1][os] = MFMA(ga1, pb1h1, yacc[1][os]);
        }
        __syncthreads();
        cur ^= 1;
    }
    // final l reduce across q-groups
    float l0 = l_run0; l0 += __shfl_xor(l0,16); l0 += __shfl_xor(l0,32);
    float l1 = l_run1; l1 += __shfl_xor(l1,16); l1 += __shfl_xor(l1,32);
    float linv0 = 1.f/l0, linv1 = 1.f/l1;
    // transpose y^T frags through (now-free) staging LDS, then coalesced global write
    f16* yl = (f16*)(ldsb + wv*8192);   // per-wave 32 rows x 128 o x 2B
    #pragma unroll
    for (int os=0;os<8;os++){
        #pragma unroll
        for (int r=0;r<4;r++){
            int o = os*16 + 4*q + r;
            *(f16*)((char*)yl + cc*256      + ((o*2) ^ ((cc&7)<<4))) = (f16)(yacc[0][os][r]*linv0);
            *(f16*)((char*)yl + (16+cc)*256 + ((o*2) ^ ((cc&7)<<4))) = (f16)(yacc[1][os][r]*linv1);
        }
    }
    #pragma unroll
    for (int p=0;p<8;p++){
        int idx = p*512 + lane*8;
        int row = idx>>7, o0 = idx&127;
        f16x8 v = *(const f16x8*)((char*)yl + row*256 + ((o0*2) ^ ((row&7)<<4)));
        *(f16x8*)(ypart + ((size_t)((sp*4+b)*NN + qrow0 + row))*CI + o0) = v;
    }
    if (lane < 16){
        size_t row0 = (size_t)(sp*4+b)*NN + qrow0 + lane;
        ml[row0*2]        = m_run0;
        ml[row0*2+1]      = l0;
        ml[(row0+16)*2]   = m_run1;
        ml[(row0+16)*2+1] = l1;
    }
}

// ---------------- K3c: fused combine + Gram/mean stats (MFMA), 64 rows/block, 256 blocks ----------------
__global__ __launch_bounds__(256) void k3c(const f16* ypart, const float* ml,
                                           f16* y, float* part, float* mupart){
    int blk = blockIdx.x; int t = threadIdx.x;     // 256 blocks
    int rloc = t>>2;                   // 0..63
    int row  = blk*64 + rloc;
    int b = row>>12, n = row & 4095;
    int o0 = (t&3)*32;
    __shared__ __align__(16) f16 ldsT[128*64];     // [o][n'] n-swizzled
    float m_s[4], l_s[4];
    #pragma unroll
    for (int s=0;s<4;s++){ size_t r2 = ((size_t)(s*4+b)*NN + n)*2; m_s[s]=ml[r2]; l_s[s]=ml[r2+1]; }
    float M = fmaxf(fmaxf(m_s[0],m_s[1]),fmaxf(m_s[2],m_s[3]));
    float w[4]; float L=0.f;
    #pragma unroll
    for (int s=0;s<4;s++){ w[s]=l_s[s]*__expf(m_s[s]-M); L+=w[s]; }
    float inv = 1.f/L;
    #pragma unroll
    for (int s=0;s<4;s++) w[s]*=inv;
    float acc[32];
    #pragma unroll
    for (int j=0;j<32;j++) acc[j]=0.f;
    #pragma unroll
    for (int s=0;s<4;s++){
        const f16* src = ypart + ((size_t)(s*4+b)*NN + n)*CI + o0;
        #pragma unroll
        for (int v=0;v<4;v++){
            f16x8 vv = *(const f16x8*)(src + v*8);
            #pragma unroll
            for (int e=0;e<8;e++) acc[v*8+e] += w[s]*(float)vv[e];
        }
    }
    f16* yo = y + (size_t)row*CI + o0;
    #pragma unroll
    for (int v=0;v<4;v++){
        f16x8 ov;
        #pragma unroll
        for (int e=0;e<8;e++) ov[e] = (f16)acc[v*8+e];
        *(f16x8*)(yo + v*8) = ov;
        #pragma unroll
        for (int e=0;e<8;e++){
            int o = o0 + v*8 + e;
            ldsT[o*64 + (rloc ^ ((o&7)<<3))] = ov[e];
        }
    }
    __syncthreads();
    // Gram partial via MFMA over 64 rows
    int wv=t>>6, lane=t&63, q=lane>>4, cc=lane&15;
    f32x4 gacc[2][8];
    #pragma unroll
    for (int a=0;a<2;a++)
        #pragma unroll
        for (int c2=0;c2<8;c2++) gacc[a][c2]=(f32x4){0,0,0,0};
    f16x8 af[2][2];
    #pragma unroll
    for (int o1t=0;o1t<2;o1t++){
        int o1 = (wv*2+o1t)*16+cc;
        #pragma unroll
        for (int kk=0;kk<2;kk++)
            af[o1t][kk] = *(const f16x8*)(ldsT + o1*64 + ((kk*32+q*8) ^ ((o1&7)<<3)));
    }
    #pragma unroll 1
    for (int o2t=0;o2t<8;o2t++){
        int o2 = o2t*16+cc;
        #pragma unroll
        for (int kk=0;kk<2;kk++){
            f16x8 bf = *(const f16x8*)(ldsT + o2*64 + ((kk*32+q*8) ^ ((o2&7)<<3)));
            gacc[0][o2t] = MFMA(af[0][kk], bf, gacc[0][o2t]);
            gacc[1][o2t] = MFMA(af[1][kk], bf, gacc[1][o2t]);
        }
    }
    float* pb = part + (size_t)blk*16384;
    #pragma unroll
    for (int o1t=0;o1t<2;o1t++){
        #pragma unroll
        for (int o2t=0;o2t<8;o2t++){
            #pragma unroll
            for (int r=0;r<4;r++)
                pb[((wv*2+o1t)*16+4*q+r)*128 + o2t*16+cc] = gacc[o1t][o2t][r];
        }
    }
    // mean partial
    if (t<128){
        float sm=0.f;
        #pragma unroll
        for (int v=0;v<8;v++){
            f16x8 vv = *(const f16x8*)(ldsT + t*64 + ((v*8) ^ ((t&7)<<3)));
            #pragma unroll
            for (int e=0;e<8;e++) sm += (float)vv[e];
        }
        mupart[blk*128 + t] = sm;
    }
}

// ---------------- K4b: chunked reduce of partials -> atomicAdd into S (pre-zeroed) ----------------
__global__ __launch_bounds__(256) void k4b_red(const float* part, const float* mupart, float* S){
    int pc = blockIdx.y;               // 8 chunks of 32 partials
    int t = threadIdx.x;
    if (blockIdx.x < 64){
        int i = blockIdx.x*256 + t;
        float s=0.f;
        #pragma unroll 1
        for (int p=pc*32; p<pc*32+32; p++) s += part[(size_t)p*16384 + i];
        atomicAdd(&S[i], s);
    } else if (t < 128){
        float s=0.f;
        #pragma unroll 1
        for (int p=pc*32; p<pc*32+32; p++) s += mupart[p*128 + t];
        atomicAdd(&S[16384+t], s);
    }
}

// ---------------- K4c: BN coefficients A[ch], B4[ch] ----------------
__global__ __launch_bounds__(128) void k4c_coef(const float* S, const float* Ww, const float* Wb,
                                                const float* gamma, const float* beta,
                                                const float* scale, float* AB){
    int ch = blockIdx.x; int t = threadIdx.x;
    const float* w = Ww + ch*CI;
    float tmp=0.f;
    const float* Srow = S + t*CI;
    #pragma unroll 1
    for (int o2=0;o2<CI;o2++) tmp += Srow[o2]*w[o2];
    float v  = w[t]*tmp;
    float mc = w[t]*S[16384 + t];
    #pragma unroll
    for (int s=1;s<64;s<<=1){ v += __shfl_xor(v,s); mc += __shfl_xor(mc,s); }
    __shared__ float red[4];
    if ((t&63)==0){ red[(t>>6)*2]=v; red[(t>>6)*2+1]=mc; }
    __syncthreads();
    if (t==0){
        float wSw = red[0]+red[2];
        float wmu = red[1]+red[3];
        const float M = 16384.f;
        float meanwy = wmu/M + Wb[ch];
        float var = wSw/M - (wmu/M)*(wmu/M);
        float inv = rsqrtf(var + 1e-5f);
        float sc = scale[0];
        float A  = sc*gamma[ch]*inv;
        float B3 = sc*(beta[ch] - meanwy*inv*gamma[ch]);
        AB[ch]     = A;
        AB[256+ch] = B3 + A*Wb[ch];
    }
}

// ---------------- K5: fused W-conv + BN + scale + residual, 512 blocks ----------------
__global__ __launch_bounds__(256) void k5_out(const f16* Wwh, const f16* y, const float* x,
                                              const float* AB, float* out){
    int ntile = blockIdx.x;      // 32
    int cht   = blockIdx.y;      // 4
    int b     = blockIdx.z;
    int wv=threadIdx.x>>6, lane=threadIdx.x&63, q=lane>>4, cc=lane&15;
    int ch0 = cht*64 + wv*16;
    f16x8 aw[4];
    const f16* wp = Wwh + ((size_t)(ch0+cc))*CI + q*8;
    #pragma unroll
    for (int kk=0;kk<4;kk++) aw[kk]=*(const f16x8*)(wp+kk*32);
    float Ar[4], Br[4];
    #pragma unroll
    for (int r=0;r<4;r++){ Ar[r]=AB[ch0+4*q+r]; Br[r]=AB[256+ch0+4*q+r]; }
    #pragma unroll 1
    for (int ns=0;ns<8;ns++){
        int n0 = ntile*128 + ns*16;
        f32x4 acc={0,0,0,0};
        const f16* yp = y + ((size_t)(b*NN + n0 + cc))*CI + q*8;
        #pragma unroll
        for (int kk=0;kk<4;kk++) acc = MFMA(aw[kk], *(const f16x8*)(yp+kk*32), acc);
        #pragma unroll
        for (int r=0;r<4;r++){
            size_t addr = ((size_t)(b*CC + ch0 + 4*q + r))*NN + n0 + cc;
            out[addr] = x[addr] + Ar[r]*acc[r] + Br[r];
        }
    }
}

extern "C" void kernel_launch(void* const* d_in, const int* in_sizes, int n_in,
                              void* d_out, int out_size, void* d_ws, size_t ws_size,
                              hipStream_t stream){
    const float* x    = (const float*)d_in[0];
    const float* g_w  = (const float*)d_in[1];
    const float* g_b  = (const float*)d_in[2];
    const float* th_w = (const float*)d_in[3];
    const float* th_b = (const float*)d_in[4];
    const float* ph_w = (const float*)d_in[5];
    const float* ph_b = (const float*)d_in[6];
    const float* W_w  = (const float*)d_in[7];
    const float* W_b  = (const float*)d_in[8];
    const float* bg   = (const float*)d_in[9];
    const float* bb   = (const float*)d_in[10];
    const float* sc   = (const float*)d_in[11];

    char* ws = (char*)d_ws;
    f16* xt  = (f16*)(ws);                                  // 8.4 MB
    f16* th  = (f16*)(ws + 8388608);                        // 4.2 MB
    f16* ph  = (f16*)(ws + 8388608 + 1*4194304);            // 4.2 MB
    f16* gt2 = (f16*)(ws + 8388608 + 2*4194304);            // 4.2 MB (tiled [b][mt][128][64], key-permuted)
    f16* y   = (f16*)(ws + 8388608 + 3*4194304);            // 4.2 MB
    f16* wh  = (f16*)(ws + 8388608 + 4*4194304);            // 256 KB
    float* ml    = (float*)(ws + 25427968);                 // 512 KB
    f16*   ypart = (f16*)(ws + 25952256);                   // 16.8 MB
    float* mupart= (float*)(ws + 42729472);                 // 128 KB
    float* part  = (float*)ws;                              // 16.8 MB overlay on xt+th+ph (dead after k3)
    float* S    = (float*)(ws + 42860544);                  // 66 KB
    float* AB   = (float*)(ws + 42926592);                  // 2 KB
    f16* th_wh = wh;
    f16* ph_wh = wh + 32768;
    f16* g_wh  = wh + 65536;
    f16* Ww_h  = wh + 98304;

    hipMemsetAsync(S, 0, 16512*sizeof(float), stream);
    hipLaunchKernelGGL(k01_xpose, dim3(64,4,4), dim3(256), 0, stream, x, xt, th_w, ph_w, g_w, W_w, wh);
    hipLaunchKernelGGL(k2_all,   dim3(128,4),   dim3(256), 0, stream, xt, th_wh, ph_wh, g_wh,
                       th_b, ph_b, g_b, th, ph, gt2);
    hipLaunchKernelGGL(k3_attn,  dim3(32,4,4),  dim3(256), 0, stream, th, ph, gt2, ypart, ml);
    hipLaunchKernelGGL(k3c,      dim3(256),     dim3(256), 0, stream, ypart, ml, y, part, mupart);
    hipLaunchKernelGGL(k4b_red,  dim3(65,8),    dim3(256), 0, stream, part, mupart, S);
    hipLaunchKernelGGL(k4c_coef, dim3(256),     dim3(128), 0, stream, S, W_w, W_b, bg, bb, sc, AB);
    hipLaunchKernelGGL(k5_out,   dim3(32,4,4),  dim3(256), 0, stream, Ww_h, y, x, AB, (float*)d_out);
}

// Round 13
// 137.579 us; speedup vs baseline: 1.2301x; 1.0114x over previous
//
#include <hip/hip_runtime.h>
#include <hip/hip_bf16.h>

#define BB 4
#define CC 256
#define CI 128
#define NN 4096

typedef _Float16 f16;
typedef __attribute__((ext_vector_type(8))) _Float16 f16x8;
typedef __attribute__((ext_vector_type(4))) _Float16 f16x4;
typedef __attribute__((ext_vector_type(4))) float f32x4;

#define MFMA(a,b,c) __builtin_amdgcn_mfma_f32_16x16x32_f16(a,b,c,0,0,0)
#define LDS3(p) ((__attribute__((address_space(3))) void*)(p))
#define GL1(p)  ((const __attribute__((address_space(1))) void*)(p))

// ---------------- K01: transpose+cast x -> xt, plus weight cast (fused k0) ----------------
__global__ __launch_bounds__(256) void k01_xpose(const float* x, f16* xt,
                                                 const float* tw, const float* pw,
                                                 const float* gw, const float* Ww, f16* wdst){
    int nt = blockIdx.x, ct = blockIdx.y, b = blockIdx.z;
    __shared__ float tile[64][65];
    int t = threadIdx.x;
    const float* src = x + ((size_t)(b*CC + ct*64))*NN + nt*64;
    #pragma unroll
    for (int k=0;k<16;k++){ int idx=t+k*256; int cl=idx>>6, nl=idx&63;
        tile[cl][nl]=src[(size_t)cl*NN + nl]; }
    __syncthreads();
    f16* dst = xt + ((size_t)(b*NN + nt*64))*CC + ct*64;
    #pragma unroll
    for (int k=0;k<16;k++){ int idx=t+k*256; int nl=idx>>6, cl=idx&63;
        dst[(size_t)nl*CC + cl] = (f16)tile[cl][nl]; }
    // fused weight cast: 1024 blocks x 128 elements = 131072
    if (t < 128){
        int blkId = blockIdx.x + 64*(blockIdx.y + 4*blockIdx.z);
        int i = blkId*128 + t;
        int j = i & 32767; int sel = i >> 15;
        const float* s = (sel==0)? tw : (sel==1)? pw : (sel==2)? gw : Ww;
        wdst[i] = (f16)s[j];
    }
}

// ---------------- K2: merged theta/phi/g projections, 512 blocks ----------------
// g output gt2[b][mt][o][64] with keys PERMUTED within each 32-half:
// key K=16j+4a+r stored at p = 8a+4j+r  (so k3's PV A-frag is one b128).
__global__ __launch_bounds__(256) void k2_all(const f16* xt, const f16* thw, const f16* phw,
                                              const f16* gwh, const float* thb, const float* phb,
                                              const float* gb, f16* th, f16* ph, f16* gt2){
    int b = blockIdx.y; int xx = blockIdx.x;
    int wv = threadIdx.x>>6, lane = threadIdx.x&63, q=lane>>4, cc=lane&15;
    if (xx < 64){
        // theta (xx<32) or phi (xx>=32), 128 rows per block
        int mat = xx>>5; int ntile = xx&31;
        int n0 = ntile*128 + wv*32;
        f16x8 aq[2][8];
        #pragma unroll
        for (int ns=0;ns<2;ns++){
            const f16* ap = xt + ((size_t)(b*NN + n0 + ns*16 + cc))*CC + q*8;
            #pragma unroll
            for (int kk=0;kk<8;kk++) aq[ns][kk] = *(const f16x8*)(ap + kk*32);
        }
        const f16* w   = mat? phw : thw;
        const float* bias = mat? phb : thb;
        f16* o = mat? ph : th;
        #pragma unroll 1
        for (int os=0;os<8;os++){
            f32x4 acc0={0,0,0,0}, acc1={0,0,0,0};
            const f16* wp = w + ((size_t)(os*16 + cc))*CC + q*8;
            #pragma unroll
            for (int kk=0;kk<8;kk++){
                f16x8 bf = *(const f16x8*)(wp + kk*32);
                acc0 = MFMA(aq[0][kk], bf, acc0);
                acc1 = MFMA(aq[1][kk], bf, acc1);
            }
            float bv = bias[os*16+cc];
            #pragma unroll
            for (int r=0;r<4;r++){
                o[((size_t)(b*NN + n0      + 4*q + r))*CI + os*16 + cc] = (f16)(acc0[r] + bv);
                o[((size_t)(b*NN + n0 + 16 + 4*q + r))*CI + os*16 + cc] = (f16)(acc1[r] + bv);
            }
        }
    } else {
        // g projection, TILED + key-permuted output
        int mt = xx - 64;
        f16x8 ag[2][8];
        #pragma unroll
        for (int os=0;os<2;os++){
            const f16* ap = gwh + ((size_t)(wv*32 + os*16 + cc))*CC + q*8;
            #pragma unroll
            for (int kk=0;kk<8;kk++) ag[os][kk] = *(const f16x8*)(ap + kk*32);
        }
        f32x4 acc[2][4];
        #pragma unroll
        for (int os=0;os<2;os++){
            #pragma unroll
            for (int ms=0;ms<4;ms++) acc[os][ms]=(f32x4){0,0,0,0};
        }
        #pragma unroll 1
        for (int kk=0;kk<8;kk++){
            #pragma unroll
            for (int ms=0;ms<4;ms++){
                f16x8 bf = *(const f16x8*)(xt + ((size_t)(b*NN + mt*64 + ms*16 + cc))*CC + kk*32 + q*8);
                acc[0][ms]=MFMA(ag[0][kk],bf,acc[0][ms]);
                acc[1][ms]=MFMA(ag[1][kk],bf,acc[1][ms]);
            }
        }
        // key within tile = ms*16+cc -> half h=ms>>1, permuted pos = 8*(cc>>2)+4*(ms&1)+(cc&3)
        #pragma unroll
        for (int os=0;os<2;os++){
            #pragma unroll
            for (int r=0;r<4;r++){
                int orow = wv*32 + os*16 + 4*q + r;
                float bv = gb[orow];
                #pragma unroll
                for (int ms=0;ms<4;ms++){
                    int pos = (ms>>1)*32 + 8*(cc>>2) + 4*(ms&1) + (cc&3);
                    gt2[((size_t)(b*64 + mt))*8192 + orow*64 + pos] = (f16)(acc[os][ms][r] + bv);
                }
            }
        }
    }
}

// ---------------- K3: flash attention, 32 q-rows/wave, KVBLK=64, swapped-P, 64KB LDS ----------------
__global__ __launch_bounds__(256, 2) void k3_attn(const f16* th, const f16* ph, const f16* gt2,
                                                  f16* ypart, float* ml){
    int qt = blockIdx.x;           // 32 q-tiles of 128 rows (4 waves x 32)
    int sp = blockIdx.y;           // 4 key splits of 1024 keys
    int b  = blockIdx.z;           // 4 batches
    int wv=threadIdx.x>>6, lane=threadIdx.x&63, q=lane>>4, cc=lane&15;
    int qrow0 = qt*128 + wv*32;
    int kv0 = sp*1024;
    int sw  = cc<<4;                        // phi read swizzle
    int rsw = (cc&7)<<4;                    // gt read swizzle (3-bit, bijective per 8-lane group)

    __shared__ __align__(16) char ldsb[65536];
    char* phL = ldsb;                 // [2][16384] phi [64 keys][256B], XOR-swizzled
    char* gtL = ldsb + 32768;         // [2][16384] gt [128 o][128B], XOR-swizzled (bits 4-6 by row&7)

    // theta B-fragments: lane holds theta[qrow0 + rb*16 + cc][d=q*8..]
    f16x8 aq[2][4];
    #pragma unroll
    for (int rb=0;rb<2;rb++){
        const f16* thp = th + ((size_t)(b*NN + qrow0 + rb*16 + cc))*CI + q*8;
        #pragma unroll
        for (int kk=0;kk<4;kk++) aq[rb][kk] = *(const f16x8*)(thp + kk*32);
    }

    const char* phg = (const char*)(ph + (size_t)b*NN*CI);
    const char* gtg = (const char*)gt2 + (size_t)b*64*16384;

    f32x4 yacc[2][8];
    #pragma unroll
    for (int rb=0;rb<2;rb++)
        #pragma unroll
        for (int os=0;os<8;os++) yacc[rb][os]=(f32x4){0,0,0,0};
    float m_run0=-1e30f, m_run1=-1e30f, l_run0=0.f, l_run1=0.f;

    // staging: 64-key tile tt -> buffer bb. LDS dest linear; global source pre-swizzled.
    auto STAGE = [&](int tt, int bb){
        int key0 = kv0 + tt*64;
        int mt  = key0 >> 6;
        char* pbase = phL + bb*16384 + wv*4096;
        char* gbase = gtL + bb*16384 + wv*4096;
        #pragma unroll
        for (int ch=0; ch<4; ch++){
            int prow = wv*16 + ch*4 + (lane>>4);
            const char* ps = phg + (size_t)(key0 + prow)*256 + (((lane&15)*16) ^ ((prow&15)<<4));
            __builtin_amdgcn_global_load_lds(GL1(ps), LDS3(pbase + ch*1024), 16, 0, 0);
            int gf = wv*4096 + ch*1024 + lane*16;
            int grow = gf>>7, gcol = gf&127;
            int scol = gcol ^ ((grow&7)<<4);
            const char* gs = gtg + (size_t)mt*16384 + grow*128 + scol;
            __builtin_amdgcn_global_load_lds(GL1(gs), LDS3(gbase + ch*1024), 16, 0, 0);
        }
    };

    STAGE(0, 0);
    __syncthreads();

    int cur = 0;
    #pragma unroll 1
    for (int it=0; it<16; ++it){
        if (it < 15) STAGE(it+1, cur^1);
        const char* pt  = phL + cur*16384;
        const char* gtt = gtL + cur*16384;
        // swapped QK^T: fa[rb][j][r] = score[key = 16j+4q+r][qrow = rb*16+cc]
        f32x4 fa[2][4];
        #pragma unroll
        for (int j=0;j<4;j++){
            f16x8 pf[4];
            #pragma unroll
            for (int kk=0;kk<4;kk++)
                pf[kk] = *(const f16x8*)(pt + (j*16+cc)*256 + ((kk*64 + q*16) ^ sw));
            fa[0][j]=(f32x4){0,0,0,0}; fa[1][j]=(f32x4){0,0,0,0};
            #pragma unroll
            for (int kk=0;kk<4;kk++){
                fa[0][j]=MFMA(pf[kk], aq[0][kk], fa[0][j]);
                fa[1][j]=MFMA(pf[kk], aq[1][kk], fa[1][j]);
            }
        }
        // per-row tile max: 15 in-lane fmax + 2 cross-q-group shuffles, per rb
        float mA0 = fmaxf(fmaxf(fa[0][0][0],fa[0][0][1]),fmaxf(fa[0][0][2],fa[0][0][3]));
        float mA1 = fmaxf(fmaxf(fa[0][1][0],fa[0][1][1]),fmaxf(fa[0][1][2],fa[0][1][3]));
        float mA2 = fmaxf(fmaxf(fa[0][2][0],fa[0][2][1]),fmaxf(fa[0][2][2],fa[0][2][3]));
        float mA3 = fmaxf(fmaxf(fa[0][3][0],fa[0][3][1]),fmaxf(fa[0][3][2],fa[0][3][3]));
        float mx0 = fmaxf(fmaxf(mA0,mA1),fmaxf(mA2,mA3));
        mx0 = fmaxf(mx0, __shfl_xor(mx0,16));
        mx0 = fmaxf(mx0, __shfl_xor(mx0,32));
        float mB0 = fmaxf(fmaxf(fa[1][0][0],fa[1][0][1]),fmaxf(fa[1][0][2],fa[1][0][3]));
        float mB1 = fmaxf(fmaxf(fa[1][1][0],fa[1][1][1]),fmaxf(fa[1][1][2],fa[1][1][3]));
        float mB2 = fmaxf(fmaxf(fa[1][2][0],fa[1][2][1]),fmaxf(fa[1][2][2],fa[1][2][3]));
        float mB3 = fmaxf(fmaxf(fa[1][3][0],fa[1][3][1]),fmaxf(fa[1][3][2],fa[1][3][3]));
        float mx1 = fmaxf(fmaxf(mB0,mB1),fmaxf(mB2,mB3));
        mx1 = fmaxf(mx1, __shfl_xor(mx1,16));
        mx1 = fmaxf(mx1, __shfl_xor(mx1,32));
        // defer-max skip (THR=3)
        float need = fmaxf(mx0 - m_run0, mx1 - m_run1);
        if (__any(need > 3.f)){
            float nm0 = fmaxf(m_run0, mx0), nm1 = fmaxf(m_run1, mx1);
            float co0 = __expf(m_run0 - nm0), co1 = __expf(m_run1 - nm1);
            m_run0 = nm0; m_run1 = nm1;
            l_run0 *= co0; l_run1 *= co1;
            #pragma unroll
            for (int os=0;os<8;os++){ yacc[0][os] *= co0; yacc[1][os] *= co1; }
        }
        #pragma unroll
        for (int j=0;j<4;j++){
            #pragma unroll
            for (int r=0;r<4;r++){
                fa[0][j][r] = __expf(fa[0][j][r]-m_run0);
                fa[1][j][r] = __expf(fa[1][j][r]-m_run1);
            }
        }
        l_run0 += ((fa[0][0][0]+fa[0][0][1]+fa[0][0][2]+fa[0][0][3])
                 + (fa[0][1][0]+fa[0][1][1]+fa[0][1][2]+fa[0][1][3]))
                + ((fa[0][2][0]+fa[0][2][1]+fa[0][2][2]+fa[0][2][3])
                 + (fa[0][3][0]+fa[0][3][1]+fa[0][3][2]+fa[0][3][3]));
        l_run1 += ((fa[1][0][0]+fa[1][0][1]+fa[1][0][2]+fa[1][0][3])
                 + (fa[1][1][0]+fa[1][1][1]+fa[1][1][2]+fa[1][1][3]))
                + ((fa[1][2][0]+fa[1][2][1]+fa[1][2][2]+fa[1][2][3])
                 + (fa[1][3][0]+fa[1][3][1]+fa[1][3][2]+fa[1][3][3]));
        // P in registers: half h frag element i=4j'+r -> fa[rb][2h+j'][r]
        f16x8 pb0h0, pb0h1, pb1h0, pb1h1;
        #pragma unroll
        for (int r=0;r<4;r++){
            pb0h0[r]=(f16)fa[0][0][r]; pb0h0[4+r]=(f16)fa[0][1][r];
            pb0h1[r]=(f16)fa[0][2][r]; pb0h1[4+r]=(f16)fa[0][3][r];
            pb1h0[r]=(f16)fa[1][0][r]; pb1h0[4+r]=(f16)fa[1][1][r];
            pb1h1[r]=(f16)fa[1][2][r]; pb1h1[4+r]=(f16)fa[1][3][r];
        }
        // PV: ga[h] read once per os, reused for both row-blocks (logical col XOR'd by row&7)
        #pragma unroll
        for (int os=0;os<8;os++){
            int row = os*16 + cc;
            f16x8 ga0 = *(const f16x8*)(gtt + row*128 + (((0<<6)|(q<<4)) ^ rsw));
            f16x8 ga1 = *(const f16x8*)(gtt + row*128 + (((1<<6)|(q<<4)) ^ rsw));
            yacc[0][os] = MFMA(ga0, pb0h0, yacc[0][os]);
            yacc[1][os] = MFMA(ga0, pb1h0, yacc[1][os]);
            yacc[0][os] = MFMA(ga1, pb0h1, yacc[0][os]);
            yacc[1][os] = MFMA(ga1, pb1h1, yacc[1][os]);
        }
        __syncthreads();
        cur ^= 1;
    }
    // final l reduce across q-groups
    float l0 = l_run0; l0 += __shfl_xor(l0,16); l0 += __shfl_xor(l0,32);
    float l1 = l_run1; l1 += __shfl_xor(l1,16); l1 += __shfl_xor(l1,32);
    float linv0 = 1.f/l0, linv1 = 1.f/l1;
    // transpose y^T frags through (now-free) staging LDS, then coalesced global write
    f16* yl = (f16*)(ldsb + wv*8192);   // per-wave 32 rows x 128 o x 2B
    #pragma unroll
    for (int os=0;os<8;os++){
        #pragma unroll
        for (int r=0;r<4;r++){
            int o = os*16 + 4*q + r;
            *(f16*)((char*)yl + cc*256      + ((o*2) ^ ((cc&7)<<4))) = (f16)(yacc[0][os][r]*linv0);
            *(f16*)((char*)yl + (16+cc)*256 + ((o*2) ^ ((cc&7)<<4))) = (f16)(yacc[1][os][r]*linv1);
        }
    }
    #pragma unroll
    for (int p=0;p<8;p++){
        int idx = p*512 + lane*8;
        int row = idx>>7, o0 = idx&127;
        f16x8 v = *(const f16x8*)((char*)yl + row*256 + ((o0*2) ^ ((row&7)<<4)));
        *(f16x8*)(ypart + ((size_t)((sp*4+b)*NN + qrow0 + row))*CI + o0) = v;
    }
    if (lane < 16){
        size_t row0 = (size_t)(sp*4+b)*NN + qrow0 + lane;
        ml[row0*2]        = m_run0;
        ml[row0*2+1]      = l0;
        ml[(row0+16)*2]   = m_run1;
        ml[(row0+16)*2+1] = l1;
    }
}

// ---------------- K3c: fused combine + Gram/mean stats (MFMA), 64 rows/block, 256 blocks ----------------
__global__ __launch_bounds__(256) void k3c(const f16* ypart, const float* ml,
                                           f16* y, float* part, float* mupart){
    int blk = blockIdx.x; int t = threadIdx.x;     // 256 blocks
    int rloc = t>>2;                   // 0..63
    int row  = blk*64 + rloc;
    int b = row>>12, n = row & 4095;
    int o0 = (t&3)*32;
    __shared__ __align__(16) f16 ldsT[128*64];     // [o][n'] n-swizzled
    float m_s[4], l_s[4];
    #pragma unroll
    for (int s=0;s<4;s++){ size_t r2 = ((size_t)(s*4+b)*NN + n)*2; m_s[s]=ml[r2]; l_s[s]=ml[r2+1]; }
    float M = fmaxf(fmaxf(m_s[0],m_s[1]),fmaxf(m_s[2],m_s[3]));
    float w[4]; float L=0.f;
    #pragma unroll
    for (int s=0;s<4;s++){ w[s]=l_s[s]*__expf(m_s[s]-M); L+=w[s]; }
    float inv = 1.f/L;
    #pragma unroll
    for (int s=0;s<4;s++) w[s]*=inv;
    float acc[32];
    #pragma unroll
    for (int j=0;j<32;j++) acc[j]=0.f;
    #pragma unroll
    for (int s=0;s<4;s++){
        const f16* src = ypart + ((size_t)(s*4+b)*NN + n)*CI + o0;
        #pragma unroll
        for (int v=0;v<4;v++){
            f16x8 vv = *(const f16x8*)(src + v*8);
            #pragma unroll
            for (int e=0;e<8;e++) acc[v*8+e] += w[s]*(float)vv[e];
        }
    }
    f16* yo = y + (size_t)row*CI + o0;
    #pragma unroll
    for (int v=0;v<4;v++){
        f16x8 ov;
        #pragma unroll
        for (int e=0;e<8;e++) ov[e] = (f16)acc[v*8+e];
        *(f16x8*)(yo + v*8) = ov;
        #pragma unroll
        for (int e=0;e<8;e++){
            int o = o0 + v*8 + e;
            ldsT[o*64 + (rloc ^ ((o&7)<<3))] = ov[e];
        }
    }
    __syncthreads();
    // Gram partial via MFMA over 64 rows
    int wv=t>>6, lane=t&63, q=lane>>4, cc=lane&15;
    f32x4 gacc[2][8];
    #pragma unroll
    for (int a=0;a<2;a++)
        #pragma unroll
        for (int c2=0;c2<8;c2++) gacc[a][c2]=(f32x4){0,0,0,0};
    f16x8 af[2][2];
    #pragma unroll
    for (int o1t=0;o1t<2;o1t++){
        int o1 = (wv*2+o1t)*16+cc;
        #pragma unroll
        for (int kk=0;kk<2;kk++)
            af[o1t][kk] = *(const f16x8*)(ldsT + o1*64 + ((kk*32+q*8) ^ ((o1&7)<<3)));
    }
    #pragma unroll 1
    for (int o2t=0;o2t<8;o2t++){
        int o2 = o2t*16+cc;
        #pragma unroll
        for (int kk=0;kk<2;kk++){
            f16x8 bf = *(const f16x8*)(ldsT + o2*64 + ((kk*32+q*8) ^ ((o2&7)<<3)));
            gacc[0][o2t] = MFMA(af[0][kk], bf, gacc[0][o2t]);
            gacc[1][o2t] = MFMA(af[1][kk], bf, gacc[1][o2t]);
        }
    }
    float* pb = part + (size_t)blk*16384;
    #pragma unroll
    for (int o1t=0;o1t<2;o1t++){
        #pragma unroll
        for (int o2t=0;o2t<8;o2t++){
            #pragma unroll
            for (int r=0;r<4;r++)
                pb[((wv*2+o1t)*16+4*q+r)*128 + o2t*16+cc] = gacc[o1t][o2t][r];
        }
    }
    // mean partial
    if (t<128){
        float sm=0.f;
        #pragma unroll
        for (int v=0;v<8;v++){
            f16x8 vv = *(const f16x8*)(ldsT + t*64 + ((v*8) ^ ((t&7)<<3)));
            #pragma unroll
            for (int e=0;e<8;e++) sm += (float)vv[e];
        }
        mupart[blk*128 + t] = sm;
    }
}

// ---------------- K4b: chunked reduce of partials -> atomicAdd into S (pre-zeroed) ----------------
__global__ __launch_bounds__(256) void k4b_red(const float* part, const float* mupart, float* S){
    int pc = blockIdx.y;               // 8 chunks of 32 partials
    int t = threadIdx.x;
    if (blockIdx.x < 64){
        int i = blockIdx.x*256 + t;
        float s=0.f;
        #pragma unroll 1
        for (int p=pc*32; p<pc*32+32; p++) s += part[(size_t)p*16384 + i];
        atomicAdd(&S[i], s);
    } else if (t < 128){
        float s=0.f;
        #pragma unroll 1
        for (int p=pc*32; p<pc*32+32; p++) s += mupart[p*128 + t];
        atomicAdd(&S[16384+t], s);
    }
}

// ---------------- K4c: BN coefficients A[ch], B4[ch] ----------------
__global__ __launch_bounds__(128) void k4c_coef(const float* S, const float* Ww, const float* Wb,
                                                const float* gamma, const float* beta,
                                                const float* scale, float* AB){
    int ch = blockIdx.x; int t = threadIdx.x;
    const float* w = Ww + ch*CI;
    float tmp=0.f;
    const float* Srow = S + t*CI;
    #pragma unroll 1
    for (int o2=0;o2<CI;o2++) tmp += Srow[o2]*w[o2];
    float v  = w[t]*tmp;
    float mc = w[t]*S[16384 + t];
    #pragma unroll
    for (int s=1;s<64;s<<=1){ v += __shfl_xor(v,s); mc += __shfl_xor(mc,s); }
    __shared__ float red[4];
    if ((t&63)==0){ red[(t>>6)*2]=v; red[(t>>6)*2+1]=mc; }
    __syncthreads();
    if (t==0){
        float wSw = red[0]+red[2];
        float wmu = red[1]+red[3];
        const float M = 16384.f;
        float meanwy = wmu/M + Wb[ch];
        float var = wSw/M - (wmu/M)*(wmu/M);
        float inv = rsqrtf(var + 1e-5f);
        float sc = scale[0];
        float A  = sc*gamma[ch]*inv;
        float B3 = sc*(beta[ch] - meanwy*inv*gamma[ch]);
        AB[ch]     = A;
        AB[256+ch] = B3 + A*Wb[ch];
    }
}

// ---------------- K5: fused W-conv + BN + scale + residual, 512 blocks ----------------
__global__ __launch_bounds__(256) void k5_out(const f16* Wwh, const f16* y, const float* x,
                                              const float* AB, float* out){
    int ntile = blockIdx.x;      // 32
    int cht   = blockIdx.y;      // 4
    int b     = blockIdx.z;
    int wv=threadIdx.x>>6, lane=threadIdx.x&63, q=lane>>4, cc=lane&15;
    int ch0 = cht*64 + wv*16;
    f16x8 aw[4];
    const f16* wp = Wwh + ((size_t)(ch0+cc))*CI + q*8;
    #pragma unroll
    for (int kk=0;kk<4;kk++) aw[kk]=*(const f16x8*)(wp+kk*32);
    float Ar[4], Br[4];
    #pragma unroll
    for (int r=0;r<4;r++){ Ar[r]=AB[ch0+4*q+r]; Br[r]=AB[256+ch0+4*q+r]; }
    #pragma unroll 1
    for (int ns=0;ns<8;ns++){
        int n0 = ntile*128 + ns*16;
        f32x4 acc={0,0,0,0};
        const f16* yp = y + ((size_t)(b*NN + n0 + cc))*CI + q*8;
        #pragma unroll
        for (int kk=0;kk<4;kk++) acc = MFMA(aw[kk], *(const f16x8*)(yp+kk*32), acc);
        #pragma unroll
        for (int r=0;r<4;r++){
            size_t addr = ((size_t)(b*CC + ch0 + 4*q + r))*NN + n0 + cc;
            out[addr] = x[addr] + Ar[r]*acc[r] + Br[r];
        }
    }
}

extern "C" void kernel_launch(void* const* d_in, const int* in_sizes, int n_in,
                              void* d_out, int out_size, void* d_ws, size_t ws_size,
                              hipStream_t stream){
    const float* x    = (const float*)d_in[0];
    const float* g_w  = (const float*)d_in[1];
    const float* g_b  = (const float*)d_in[2];
    const float* th_w = (const float*)d_in[3];
    const float* th_b = (const float*)d_in[4];
    const float* ph_w = (const float*)d_in[5];
    const float* ph_b = (const float*)d_in[6];
    const float* W_w  = (const float*)d_in[7];
    const float* W_b  = (const float*)d_in[8];
    const float* bg   = (const float*)d_in[9];
    const float* bb   = (const float*)d_in[10];
    const float* sc   = (const float*)d_in[11];

    char* ws = (char*)d_ws;
    f16* xt  = (f16*)(ws);                                  // 8.4 MB
    f16* th  = (f16*)(ws + 8388608);                        // 4.2 MB
    f16* ph  = (f16*)(ws + 8388608 + 1*4194304);            // 4.2 MB
    f16* gt2 = (f16*)(ws + 8388608 + 2*4194304);            // 4.2 MB (tiled [b][mt][128][64], key-permuted)
    f16* y   = (f16*)(ws + 8388608 + 3*4194304);            // 4.2 MB
    f16* wh  = (f16*)(ws + 8388608 + 4*4194304);            // 256 KB
    float* ml    = (float*)(ws + 25427968);                 // 512 KB
    f16*   ypart = (f16*)(ws + 25952256);                   // 16.8 MB
    float* mupart= (float*)(ws + 42729472);                 // 128 KB
    float* part  = (float*)ws;                              // 16.8 MB overlay on xt+th+ph (dead after k3)
    float* S    = (float*)(ws + 42860544);                  // 66 KB
    float* AB   = (float*)(ws + 42926592);                  // 2 KB
    f16* th_wh = wh;
    f16* ph_wh = wh + 32768;
    f16* g_wh  = wh + 65536;
    f16* Ww_h  = wh + 98304;

    hipMemsetAsync(S, 0, 16512*sizeof(float), stream);
    hipLaunchKernelGGL(k01_xpose, dim3(64,4,4), dim3(256), 0, stream, x, xt, th_w, ph_w, g_w, W_w, wh);
    hipLaunchKernelGGL(k2_all,   dim3(128,4),   dim3(256), 0, stream, xt, th_wh, ph_wh, g_wh,
                       th_b, ph_b, g_b, th, ph, gt2);
    hipLaunchKernelGGL(k3_attn,  dim3(32,4,4),  dim3(256), 0, stream, th, ph, gt2, ypart, ml);
    hipLaunchKernelGGL(k3c,      dim3(256),     dim3(256), 0, stream, ypart, ml, y, part, mupart);
    hipLaunchKernelGGL(k4b_red,  dim3(65,8),    dim3(256), 0, stream, part, mupart, S);
    hipLaunchKernelGGL(k4c_coef, dim3(256),     dim3(128), 0, stream, S, W_w, W_b, bg, bb, sc, AB);
    hipLaunchKernelGGL(k5_out,   dim3(32,4,4),  dim3(256), 0, stream, Ww_h, y, x, AB, (float*)d_out);
}